// Round 11
// baseline (437.879 us; speedup 1.0000x reference)
//
#include <hip/hip_runtime.h>
#include <hip/hip_bf16.h>
#include <hip/hip_fp16.h>

// VQ codebook lookup via fp16 MFMA + margin-based candidate recheck.
// x[16,256,32,32] f32, E[256,8192] f32, N=16384 tokens, K=8192 codes.
// S = fp16(x)·fp16(e) via mfma_f32_16x16x32_f16 (fp16 products exact in
// fp32): dist-err sigma ~7.8e-4, pairwise ~1.1e-3; MARGIN 0.02 ~ 18 sigma.
// Flagged tokens: block top-1s in window -> exact pair recheck; blocks with
// top-2 in window -> exact 256-code BLOCK scan. Exact path = ascending-d
// fmaf chain (validated R1-R8).
//
// R20: all-register fragment double-buffer, zero LDS in the K-loop.
//   R19 accounting: wall 1356 cy/step vs LDS-port demand ~1250 cy (8 ds_read
//   + 5 gload_lds x 12 waves) -> LDS-port-bound. And B staging never crosses
//   waves (wave w stages exactly the slots it reads) -> the whole B LDS
//   round-trip is pass-through of L2-resident data. A's 4x sharing is cheap
//   to forgo (FETCH stays ~21MB, all XCD-L2-local).
//   Fix vs R17 (direct-global, 256us FAIL): R17 had no prefetch distance —
//   loads consumed immediately, L2 latency exposed per step. R20 ping-pongs
//   afrag/bfrag[2][4] (static indices under full unroll): step t issues
//   step t+1's 8 global_load_dwordx4 BEFORE t's MFMAs -> full-step cover.
//   No barriers in loop. LDS = 2.5KB reduction arrays only.
//   Kept (validated): fp16 single-pass (R14), packed-u32 top-2 epilogue +
//   4-way write split (R17/R19), XCD both-operand L2 residency, geometry
//   64tok x 256codes per block, wave 64x64.
// Downstream kernels and pd1/pi1/pd2 layout unchanged from R19 (absmax 0).

#define D_   256
#define HW_  1024
#define N_   16384
#define K_   8192
#define NB_  32              // 32 code-blocks of 256
#define MARGIN 0.02f         // ~18 sigma of fp16 approx-error difference

#define OUT1_OFF 4194304     // B*D*H*W
#define IND_OFF  8388608

typedef __attribute__((ext_vector_type(8))) _Float16 f16x8;  // 8 f16 = 4 VGPR
typedef __attribute__((ext_vector_type(4))) float f32x4;

__device__ __forceinline__ unsigned long long pack_dk(float dist, int k) {
    unsigned db = __float_as_uint(dist);
    unsigned mono = (db & 0x80000000u) ? ~db : (db | 0x80000000u);
    return ((unsigned long long)mono << 32) | (unsigned)k;
}

// ---------------- codebook column norms + counter zeroing -------------------
__global__ __launch_bounds__(256)
void cnorm_kernel(const float* __restrict__ E, float* __restrict__ c,
                  int* __restrict__ counters) {
    if (blockIdx.x == 0 && threadIdx.x < 2) counters[threadIdx.x] = 0;
    __shared__ float part[8][32];
    const int tid = threadIdx.x;
    const int cl = tid & 31, q = tid >> 5;
    const int k = blockIdx.x * 32 + cl;
    float s = 0.f;
    #pragma unroll 8
    for (int d = q * 32; d < q * 32 + 32; ++d) {
        float v = E[(size_t)d * K_ + k];
        s = fmaf(v, v, s);
    }
    part[q][cl] = s;
    __syncthreads();
    if (tid < 32) {   // fixed combine order: deterministic
        float t0 = (part[0][tid] + part[1][tid]) + (part[2][tid] + part[3][tid]);
        float t1 = (part[4][tid] + part[5][tid]) + (part[6][tid] + part[7][tid]);
        c[blockIdx.x * 32 + tid] = t0 + t1;
    }
}

// ---------------- prep: x fp32 -> fp16 plane, transposed to token-major -----
__global__ __launch_bounds__(256)
void prep_x(const float* __restrict__ x, ushort* __restrict__ xf) {
    __shared__ float t[32][33];
    const int s0 = blockIdx.x * 32, d0 = blockIdx.y * 32, b = blockIdx.z;
    const int tid = threadIdx.x;
    #pragma unroll
    for (int j = 0; j < 4; ++j) {
        int i = tid + 256 * j; int dd = i >> 5, ss = i & 31;
        t[dd][ss] = x[(size_t)b * 262144 + (size_t)(d0 + dd) * 1024 + s0 + ss];
    }
    __syncthreads();
    #pragma unroll
    for (int j = 0; j < 4; ++j) {
        int i = tid + 256 * j; int ss = i >> 5, dd = i & 31;
        _Float16 h = (_Float16)t[dd][ss];          // RN f32->f16
        size_t o = (size_t)(b * 1024 + s0 + ss) * D_ + d0 + dd;
        xf[o] = *(ushort*)&h;
    }
}

// E[d][k] -> ef[k][d] fp16
__global__ __launch_bounds__(256)
void prep_e(const float* __restrict__ E, ushort* __restrict__ ef) {
    __shared__ float t[32][33];
    const int k0 = blockIdx.x * 32, d0 = blockIdx.y * 32;
    const int tid = threadIdx.x;
    #pragma unroll
    for (int j = 0; j < 4; ++j) {
        int i = tid + 256 * j; int dd = i >> 5, kk = i & 31;
        t[dd][kk] = E[(size_t)(d0 + dd) * K_ + k0 + kk];
    }
    __syncthreads();
    #pragma unroll
    for (int j = 0; j < 4; ++j) {
        int i = tid + 256 * j; int kk = i >> 5, dd = i & 31;
        _Float16 h = (_Float16)t[dd][kk];
        ef[(size_t)(k0 + kk) * D_ + d0 + dd] = *(ushort*)&h;
    }
}

// ---------------- MFMA distance + per-token top-2 per 256-code block --------
// grid 8192 flat, XCD-partitioned. block 256 = 4 waves, block tile 64 tokens
// x 256 codes, wave tile 64x64 (acc[4][4]). All-register fragment dbuf:
// step t+1's 8 global_load_dwordx4 issued before t's MFMAs (full-step
// prefetch cover, L2-resident slices). No LDS/barriers in loop.
// Packed-u32 top-2 epilogue (R17/R19-validated).
__global__ __launch_bounds__(256, 3)
void mfma_kernel(const ushort* __restrict__ xf,
                 const ushort* __restrict__ ef,
                 const float* __restrict__ c,
                 float* __restrict__ pd1, int* __restrict__ pi1, float* __restrict__ pd2) {
    __shared__ unsigned red1[320], red2[320];      // [64][5] padded

    const int tid = threadIdx.x;
    // XCD partition: xcd owns mb in [xcd*32, xcd*32+32); nb slow within xcd.
    const int bid = blockIdx.x;
    const int xcd = bid & 7, rr = bid >> 3;
    const int nb = rr >> 5, mb = xcd * 32 + (rr & 31);
    const int n0 = mb * 64, k0 = nb * 256;
    const int lane = tid & 63, w = tid >> 6;       // w = code quadrant 0..3
    const int l15 = lane & 15, lq = lane >> 4;

    // fragment base pointers (16B/lane, 16B-aligned) — R17-validated pattern
    const ushort* ap[4]; const ushort* bp[4];
    #pragma unroll
    for (int mt = 0; mt < 4; ++mt)
        ap[mt] = xf + (size_t)(n0 + mt * 16 + l15) * D_ + lq * 8;
    #pragma unroll
    for (int nt = 0; nt < 4; ++nt)
        bp[nt] = ef + (size_t)(k0 + w * 64 + nt * 16 + l15) * D_ + lq * 8;

    f32x4 acc[4][4];
    #pragma unroll
    for (int mt = 0; mt < 4; ++mt)
        #pragma unroll
        for (int nt = 0; nt < 4; ++nt) acc[mt][nt] = (f32x4){0.f, 0.f, 0.f, 0.f};

    // register ping-pong fragment buffers; all indices static under full unroll
    f16x8 afrag[2][4], bfrag[2][4];
    #pragma unroll
    for (int mt = 0; mt < 4; ++mt) afrag[0][mt] = *(const f16x8*)(ap[mt]);
    #pragma unroll
    for (int nt = 0; nt < 4; ++nt) bfrag[0][nt] = *(const f16x8*)(bp[nt]);

    #pragma unroll
    for (int db = 0; db < 8; ++db) {
        const int cur = db & 1;
        if (db < 7) {   // issue step t+1's loads BEFORE t's MFMAs
            const int dn = (db + 1) * 32;
            #pragma unroll
            for (int mt = 0; mt < 4; ++mt)
                afrag[cur ^ 1][mt] = *(const f16x8*)(ap[mt] + dn);
            #pragma unroll
            for (int nt = 0; nt < 4; ++nt)
                bfrag[cur ^ 1][nt] = *(const f16x8*)(bp[nt] + dn);
        }
        #pragma unroll
        for (int nt = 0; nt < 4; ++nt)
            #pragma unroll
            for (int mt = 0; mt < 4; ++mt)
                acc[mt][nt] = __builtin_amdgcn_mfma_f32_16x16x32_f16(
                    afrag[cur][mt], bfrag[cur][nt], acc[mt][nt], 0, 0, 0);
    }

    float cv[4];
    #pragma unroll
    for (int nt = 0; nt < 4; ++nt) cv[nt] = c[k0 + w * 64 + nt * 16 + l15];

    // packed top-2: key = ((uint)((dist+128)*2^15) << 8) | code8.
    // dist bounded |dist| <= 1+2*||x||·||e|| < 40 << 128; quant step ~8e-6
    // absorbed by MARGIN (18 sigma). min = dist asc then code asc
    // (= first-min ties). R17/R19-validated (absmax 0).
    unsigned m1[16], m2[16];
    #pragma unroll
    for (int mt = 0; mt < 4; ++mt)
        #pragma unroll
        for (int r = 0; r < 4; ++r) {
            int p = mt * 4 + r;
            unsigned b1 = 0xFFFFFFFFu, b2v = 0xFFFFFFFFu;
            #pragma unroll
            for (int nt = 0; nt < 4; ++nt) {
                float dist = fmaf(-2.f, acc[mt][nt][r], cv[nt]);
                unsigned u = (unsigned)fmaf(dist, 32768.f, 4194304.f); // (d+128)*2^15
                unsigned key = (u << 8) | (unsigned)(w * 64 + nt * 16 + l15);
                unsigned t = key > b1 ? key : b1;    // max
                b1 = key < b1 ? key : b1;            // min
                b2v = t < b2v ? t : b2v;             // min
            }
            m1[p] = b1; m2[p] = b2v;
        }
    #pragma unroll
    for (int s = 1; s < 16; s <<= 1) {
        #pragma unroll
        for (int p = 0; p < 16; ++p) {
            unsigned n1 = (unsigned)__shfl_xor((int)m1[p], s);
            unsigned n2 = (unsigned)__shfl_xor((int)m2[p], s);
            unsigned t = m1[p] > n1 ? m1[p] : n1;
            m1[p] = m1[p] < n1 ? m1[p] : n1;
            unsigned mn = n2 < t ? n2 : t;
            m2[p] = m2[p] < mn ? m2[p] : mn;         // min3(m2, n2, t)
        }
    }
    if (l15 == 0) {
        #pragma unroll
        for (int mt = 0; mt < 4; ++mt)
            #pragma unroll
            for (int r = 0; r < 4; ++r) {
                int p = mt * 4 + r;
                int t = mt * 16 + lq * 4 + r;
                red1[t * 5 + w] = m1[p]; red2[t * 5 + w] = m2[p];
            }
    }
    __syncthreads();
    if (tid < 64) {   // order-independent min/max merge: deterministic
        unsigned a1 = red1[tid * 5], a2v = red2[tid * 5];
        #pragma unroll
        for (int q = 1; q < 4; ++q) {
            unsigned n1 = red1[tid * 5 + q], n2 = red2[tid * 5 + q];
            unsigned t = a1 > n1 ? a1 : n1;
            a1 = a1 < n1 ? a1 : n1;
            unsigned mn = n2 < t ? n2 : t;
            a2v = a2v < mn ? a2v : mn;
        }
        size_t o = (size_t)nb * N_ + n0 + tid;
        pd1[o] = (float)(a1 >> 8) * (1.f / 32768.f) - 128.f;
        pi1[o] = k0 + (int)(a1 & 255u);
        pd2[o] = (float)(a2v >> 8) * (1.f / 32768.f) - 128.f;
    }
}

// ---------------- merge 32 blocks; enumerate pair/scan candidates -----------
// counters[0]=pairs, [1]=block-scan tasks. Coverage: true winner j in block B
// is B's top-1 (pd1<=W -> pair) or has obs >= pd2_B, forcing pd2_B<=W -> B
// gets an exact 256-code scan which covers ANY rank in B.
__global__ __launch_bounds__(256)
void merge_flag(const float* __restrict__ pd1, const int* __restrict__ pi1,
                const float* __restrict__ pd2,
                int* __restrict__ idx, int* __restrict__ counters,
                unsigned long long* __restrict__ key,
                unsigned int* __restrict__ pairs, unsigned int* __restrict__ scans) {
    int n = blockIdx.x * 256 + threadIdx.x;
    float a = 3.4e38f, b2 = 3.4e38f; int ai = -1;
    for (int nb = 0; nb < NB_; ++nb) {
        float n1 = pd1[(size_t)nb * N_ + n];
        int   ni = pi1[(size_t)nb * N_ + n];
        float n2 = pd2[(size_t)nb * N_ + n];
        if (n1 < a) { b2 = fminf(a, n2); a = n1; ai = ni; }
        else        { b2 = fminf(b2, n1); }
    }
    if (b2 - a < MARGIN) {
        const float W = a + MARGIN;
        key[n] = ~0ULL;
        idx[n] = 0x80000000 | ai;          // flagged: resolve from key later
        for (int nb = 0; nb < NB_; ++nb) {
            if (pd2[(size_t)nb * N_ + n] <= W) {
                int q = atomicAdd(&counters[1], 1);
                scans[q] = ((unsigned)n << 5) | (unsigned)nb;
            } else if (pd1[(size_t)nb * N_ + n] <= W) {
                int q = atomicAdd(&counters[0], 1);
                pairs[q] = ((unsigned)n << 13) | (unsigned)pi1[(size_t)nb * N_ + n];
            }
        }
    } else {
        idx[n] = ai;
    }
}

// ---------------- fused exact fp32 recheck (pairs + block scans) ------------
// blocks [0,128): 4 threads per (token, candidate); blocks [128,384): one
// (token, 256-code block) exact scan per task, E rows coalesced.
__global__ __launch_bounds__(256)
void recheck(const float* __restrict__ x, const float* __restrict__ E,
             const float* __restrict__ c, const unsigned int* __restrict__ pairs,
             const unsigned int* __restrict__ scans, const int* __restrict__ counters,
             unsigned long long* __restrict__ key) {
    if (blockIdx.x < 128) {
        int items = counters[0] * 4;
        for (int it = blockIdx.x * 256 + threadIdx.x; it < items; it += 128 * 256) {
            int p = it >> 2, q = it & 3;   // quads stay intact: stride % 4 == 0
            unsigned v = pairs[p];
            int n = v >> 13, k = v & 8191;
            int b = n >> 10, s = n & 1023;
            const float* xb = x + (size_t)b * 262144 + s;
            const float* eb = E + k;
            float acc = 0.f;
            const int d0 = q * 64;
            #pragma unroll 8
            for (int d = d0; d < d0 + 64; ++d)
                acc = fmaf(xb[(size_t)d * HW_], eb[(size_t)d * K_], acc);
            float o1 = __shfl_xor(acc, 1); float s2 = acc + o1;
            float o2 = __shfl_xor(s2, 2);  float tot = s2 + o2;   // ((q0+q1)+(q2+q3))
            if (q == 0) atomicMin(key + n, pack_dk(fmaf(-2.f, tot, c[k]), k));
        }
    } else {
        int cnt = counters[1];
        for (int t = blockIdx.x - 128; t < cnt; t += 256) {
            unsigned v = scans[t];
            int n = v >> 5, nb = v & 31;
            int k = nb * 256 + threadIdx.x;
            int b = n >> 10, s = n & 1023;
            const float* xb = x + (size_t)b * 262144 + s;
            float acc = 0.f;
            #pragma unroll 4
            for (int d = 0; d < D_; ++d)          // ascending d: exact ref chain
                acc = fmaf(xb[(size_t)d * HW_], E[(size_t)d * K_ + k], acc);
            float dist = fmaf(-2.f, acc, c[k]);
            atomicMin(key + n, pack_dk(dist, k));  // (dist,k) lex-min: first-min ties
        }
    }
}

// ---------------- gather + write outputs (float4, fixup via sign bit) -------
// grid (256, 4): blockIdx.y selects a 64-d band -> 4 blocks/CU (was 1,
// latency-bound gather).
__global__ __launch_bounds__(256)
void write_kernel(const float* __restrict__ x, const float* __restrict__ E,
                  const int* __restrict__ idx, const unsigned long long* __restrict__ key,
                  float* __restrict__ out) {
    __shared__ int kst[64];
    const int n0 = blockIdx.x * 64;
    const int b = n0 >> 10, s0 = n0 & 1023;
    const int tid = threadIdx.x;
    if (tid < 64) {
        int v = idx[n0 + tid];
        int k = (v < 0) ? (int)(key[n0 + tid] & 8191ULL) : v;
        kst[tid] = k;
        if (blockIdx.y == 0) out[IND_OFF + n0 + tid] = (float)k;
    }
    __syncthreads();
    const int g = tid & 15;               // float4 group of 4 tokens
    const int d0 = tid >> 4;              // 16 d-streams
    const int dband = blockIdx.y * 64;    // this block's 64-d band
    const int ka = kst[g * 4], kb2 = kst[g * 4 + 1], kc = kst[g * 4 + 2], kd = kst[g * 4 + 3];
    const float* xb = x + (size_t)b * 262144 + s0 + g * 4;
    float* o0 = out + (size_t)b * 262144 + s0 + g * 4;
    float* o1 = o0 + OUT1_OFF;
    for (int d = dband + d0; d < dband + 64; d += 16) {
        const float* er = E + (size_t)d * K_;
        float4 xv = *(const float4*)(xb + (size_t)d * HW_);
        float4 q;
        q.x = er[ka]; q.y = er[kb2]; q.z = er[kc]; q.w = er[kd];
        float4 r;                          // x + (q - x): replicate jnp fp32 rounding
        r.x = xv.x + (q.x - xv.x); r.y = xv.y + (q.y - xv.y);
        r.z = xv.z + (q.z - xv.z); r.w = xv.w + (q.w - xv.w);
        *(float4*)(o0 + (size_t)d * HW_) = r;
        *(float4*)(o1 + (size_t)d * HW_) = q;
    }
}

extern "C" void kernel_launch(void* const* d_in, const int* in_sizes, int n_in,
                              void* d_out, int out_size, void* d_ws, size_t ws_size,
                              hipStream_t stream) {
    const float* x = (const float*)d_in[0];
    const float* E = (const float*)d_in[1];
    float* out = (float*)d_out;

    char* p = (char*)d_ws;
    ushort* xf = (ushort*)p;                 p += (size_t)N_ * D_ * 2;   // 8 MB
    ushort* ef = (ushort*)p;                 p += (size_t)K_ * D_ * 2;   // 4 MB
    float*  c  = (float*)p;                  p += (size_t)K_ * 4;
    float*  pd1 = (float*)p;                 p += (size_t)NB_ * N_ * 4;  // 2 MB
    int*    pi1 = (int*)p;                   p += (size_t)NB_ * N_ * 4;
    float*  pd2 = (float*)p;                 p += (size_t)NB_ * N_ * 4;
    int*    idx = (int*)p;                   p += (size_t)N_ * 4;
    unsigned long long* key = (unsigned long long*)p; p += (size_t)N_ * 8;
    unsigned int* pairs = (unsigned int*)p;  p += (size_t)524288 * 4;    // 2 MB cap
    unsigned int* scans = (unsigned int*)p;  p += (size_t)524288 * 4;    // 2 MB cap
    int*    counters = (int*)p;              p += 256;

    cnorm_kernel<<<K_ / 32, 256, 0, stream>>>(E, c, counters);
    prep_x<<<dim3(32, 8, 16), 256, 0, stream>>>(x, xf);
    prep_e<<<dim3(256, 8), 256, 0, stream>>>(E, ef);
    mfma_kernel<<<8192, 256, 0, stream>>>(xf, ef, c, pd1, pi1, pd2);
    merge_flag<<<N_ / 256, 256, 0, stream>>>(pd1, pi1, pd2, idx, counters, key, pairs, scans);
    recheck<<<384, 256, 0, stream>>>(x, E, c, pairs, scans, counters, key);
    write_kernel<<<dim3(256, 4), 256, 0, stream>>>(x, E, idx, key, out);
}

// Round 12
// 356.488 us; speedup vs baseline: 1.2283x; 1.2283x over previous
//
#include <hip/hip_runtime.h>
#include <hip/hip_bf16.h>
#include <hip/hip_fp16.h>

// VQ codebook lookup via fp16 MFMA + margin-based candidate recheck.
// x[16,256,32,32] f32, E[256,8192] f32, N=16384 tokens, K=8192 codes.
// S = fp16(x)·fp16(e) via mfma_f32_16x16x32_f16 (fp16 products exact in
// fp32): dist-err sigma ~7.8e-4, pairwise ~1.1e-3; MARGIN 0.02 ~ 18 sigma.
// Flagged tokens: block top-1s in window -> exact pair recheck; blocks with
// top-2 in window -> exact 256-code BLOCK scan. Exact path = ascending-d
// fmaf chain (validated R1-R8).
//
// R21 = R19 with B-only LDS staging + A fragments direct from L2:
//   R20 post-mortem: hipcc sinks plain global loads to first use (VGPR=72
//   proved the register ping-pong collapsed; 255us = R17's 256us). So keep
//   B in the proven gload_lds dbuf pipe, and take only A out of LDS:
//   - A fragments: 4x global_load_dwordx4/wave/step, 16B/lane contiguous
//     (exact pattern R13 ran at speed for a_l; R17/R20 absmax-0 values).
//     Only 4 in-step-latency-exposed loads (R17's failure had all 8).
//   - LDS 43.5 -> 34.5 KB -> 4 blocks/CU (launch_bounds 256,4): 4 barrier
//     domains/CU (was 3) — more cross-block convoy cover.
//   - ds_reads/wave-step 8 -> 4; staged bytes 20 -> 16 KB/step.
//   Kept (validated): fp16 single-pass (R14), 2-phase dbuf __syncthreads
//   loop (R14/R19), packed-u32 top-2 epilogue + 4-way write split
//   (R17/R19), XCD both-operand L2 residency, 64tok x 256codes per block.
// Downstream kernels and pd1/pi1/pd2 layout unchanged from R19 (absmax 0).

#define D_   256
#define HW_  1024
#define N_   16384
#define K_   8192
#define NB_  32              // 32 code-blocks of 256
#define MARGIN 0.02f         // ~18 sigma of fp16 approx-error difference

#define OUT1_OFF 4194304     // B*D*H*W
#define IND_OFF  8388608

typedef __attribute__((ext_vector_type(8))) _Float16 f16x8;  // 8 f16 = 4 VGPR
typedef __attribute__((ext_vector_type(4))) float f32x4;

__device__ __forceinline__ unsigned long long pack_dk(float dist, int k) {
    unsigned db = __float_as_uint(dist);
    unsigned mono = (db & 0x80000000u) ? ~db : (db | 0x80000000u);
    return ((unsigned long long)mono << 32) | (unsigned)k;
}

// async global->LDS DMA: lane i of the wave lands at ldsbase + 16*i.
__device__ __forceinline__ void async_copy16(const void* g, void* l) {
    __builtin_amdgcn_global_load_lds(
        (const __attribute__((address_space(1))) void*)g,
        (__attribute__((address_space(3))) void*)l, 16, 0, 0);
}

// ---------------- codebook column norms + counter zeroing -------------------
__global__ __launch_bounds__(256)
void cnorm_kernel(const float* __restrict__ E, float* __restrict__ c,
                  int* __restrict__ counters) {
    if (blockIdx.x == 0 && threadIdx.x < 2) counters[threadIdx.x] = 0;
    __shared__ float part[8][32];
    const int tid = threadIdx.x;
    const int cl = tid & 31, q = tid >> 5;
    const int k = blockIdx.x * 32 + cl;
    float s = 0.f;
    #pragma unroll 8
    for (int d = q * 32; d < q * 32 + 32; ++d) {
        float v = E[(size_t)d * K_ + k];
        s = fmaf(v, v, s);
    }
    part[q][cl] = s;
    __syncthreads();
    if (tid < 32) {   // fixed combine order: deterministic
        float t0 = (part[0][tid] + part[1][tid]) + (part[2][tid] + part[3][tid]);
        float t1 = (part[4][tid] + part[5][tid]) + (part[6][tid] + part[7][tid]);
        c[blockIdx.x * 32 + tid] = t0 + t1;
    }
}

// ---------------- prep: x fp32 -> fp16 plane, transposed to token-major -----
__global__ __launch_bounds__(256)
void prep_x(const float* __restrict__ x, ushort* __restrict__ xf) {
    __shared__ float t[32][33];
    const int s0 = blockIdx.x * 32, d0 = blockIdx.y * 32, b = blockIdx.z;
    const int tid = threadIdx.x;
    #pragma unroll
    for (int j = 0; j < 4; ++j) {
        int i = tid + 256 * j; int dd = i >> 5, ss = i & 31;
        t[dd][ss] = x[(size_t)b * 262144 + (size_t)(d0 + dd) * 1024 + s0 + ss];
    }
    __syncthreads();
    #pragma unroll
    for (int j = 0; j < 4; ++j) {
        int i = tid + 256 * j; int ss = i >> 5, dd = i & 31;
        _Float16 h = (_Float16)t[dd][ss];          // RN f32->f16
        size_t o = (size_t)(b * 1024 + s0 + ss) * D_ + d0 + dd;
        xf[o] = *(ushort*)&h;
    }
}

// E[d][k] -> ef[k][d] fp16
__global__ __launch_bounds__(256)
void prep_e(const float* __restrict__ E, ushort* __restrict__ ef) {
    __shared__ float t[32][33];
    const int k0 = blockIdx.x * 32, d0 = blockIdx.y * 32;
    const int tid = threadIdx.x;
    #pragma unroll
    for (int j = 0; j < 4; ++j) {
        int i = tid + 256 * j; int dd = i >> 5, kk = i & 31;
        t[dd][kk] = E[(size_t)(d0 + dd) * K_ + k0 + kk];
    }
    __syncthreads();
    #pragma unroll
    for (int j = 0; j < 4; ++j) {
        int i = tid + 256 * j; int kk = i >> 5, dd = i & 31;
        _Float16 h = (_Float16)t[dd][kk];
        ef[(size_t)(k0 + kk) * D_ + d0 + dd] = *(ushort*)&h;
    }
}

// ---------------- MFMA distance + per-token top-2 per 256-code block --------
// grid 8192 flat, XCD-partitioned. block 256 = 4 waves, block tile 64 tokens
// x 256 codes, wave tile 64x64 (acc[4][4]). B: 2-phase LDS dbuf (gload_lds,
// prefetch t+1 before compute of t, one __syncthreads per step). A: direct
// 16B/lane global loads per step (L2-resident; R13-validated pattern).
// LDS rows = 64B of 4x16B chunks, chunk pos = chunk ^ ((row>>1)&3).
// Packed-u32 top-2 epilogue (R17/R19-validated).
__global__ __launch_bounds__(256, 4)
void mfma_kernel(const ushort* __restrict__ xf,
                 const ushort* __restrict__ ef,
                 const float* __restrict__ c,
                 float* __restrict__ pd1, int* __restrict__ pi1, float* __restrict__ pd2) {
    __shared__ __align__(16) ushort Bb[2][8192];   // [2][256*32] 32 KB
    __shared__ unsigned red1[320], red2[320];      // [64][5] padded

    const int tid = threadIdx.x;
    // XCD partition: xcd owns mb in [xcd*32, xcd*32+32); nb slow within xcd.
    const int bid = blockIdx.x;
    const int xcd = bid & 7, rr = bid >> 3;
    const int nb = rr >> 5, mb = xcd * 32 + (rr & 31);
    const int n0 = mb * 64, k0 = nb * 256;
    const int lane = tid & 63, w = tid >> 6;       // w = code quadrant 0..3
    const int l15 = lane & 15, lq = lane >> 4;

    // B staging: 4 gload_lds per wave per step
    size_t boff[4]; int bdst[4];
    #pragma unroll
    for (int g = 0; g < 4; ++g) {
        int slot = (w * 4 + g) * 64 + lane;
        int t = slot >> 2, cp = slot & 3;
        int cs = cp ^ ((t >> 1) & 3);
        boff[g] = (size_t)(k0 + t) * D_ + cs * 8;
        bdst[g] = (w * 4 + g) * 512;
    }
    // B fragment read offsets (XOR matches staging swizzle)
    int bro[4];
    #pragma unroll
    for (int nt = 0; nt < 4; ++nt) {
        int R = w * 64 + nt * 16 + l15;
        bro[nt] = R * 32 + ((lq ^ ((R >> 1) & 3)) * 8);
    }
    // A fragment base pointers: 16B/lane contiguous (R13-validated pattern)
    const ushort* ap[4];
    #pragma unroll
    for (int mt = 0; mt < 4; ++mt)
        ap[mt] = xf + (size_t)(n0 + mt * 16 + l15) * D_ + lq * 8;

    f32x4 acc[4][4];
    #pragma unroll
    for (int mt = 0; mt < 4; ++mt)
        #pragma unroll
        for (int nt = 0; nt < 4; ++nt) acc[mt][nt] = (f32x4){0.f, 0.f, 0.f, 0.f};

    // prologue: stage B step 0 into buffer 0
    #pragma unroll
    for (int g = 0; g < 4; ++g)
        async_copy16(ef + boff[g], &Bb[0][bdst[g]]);
    __syncthreads();

    #pragma unroll
    for (int db = 0; db < 8; ++db) {
        const int cur = db & 1;
        const int d0 = db * 32;
        // A fragments for THIS step: direct global (L2-resident slice)
        f16x8 a[4];
        #pragma unroll
        for (int mt = 0; mt < 4; ++mt)
            a[mt] = *(const f16x8*)(ap[mt] + d0);
        if (db < 7) {   // prefetch B step t+1 into the other buffer
            const int dn = d0 + 32;
            #pragma unroll
            for (int g = 0; g < 4; ++g)
                async_copy16(ef + boff[g] + dn, &Bb[cur ^ 1][bdst[g]]);
        }
        f16x8 b[4];
        #pragma unroll
        for (int nt = 0; nt < 4; ++nt)
            b[nt] = *(const f16x8*)&Bb[cur][bro[nt]];
        #pragma unroll
        for (int nt = 0; nt < 4; ++nt)
            #pragma unroll
            for (int mt = 0; mt < 4; ++mt)
                acc[mt][nt] = __builtin_amdgcn_mfma_f32_16x16x32_f16(a[mt], b[nt], acc[mt][nt], 0, 0, 0);
        __syncthreads();   // drains prefetch; protects buffer reuse
    }

    float cv[4];
    #pragma unroll
    for (int nt = 0; nt < 4; ++nt) cv[nt] = c[k0 + w * 64 + nt * 16 + l15];

    // packed top-2: key = ((uint)((dist+128)*2^15) << 8) | code8.
    // dist bounded |dist| <= 1+2*||x||·||e|| < 40 << 128; quant step ~8e-6
    // absorbed by MARGIN (18 sigma). min = dist asc then code asc
    // (= first-min ties). R17/R19-validated (absmax 0).
    unsigned m1[16], m2[16];
    #pragma unroll
    for (int mt = 0; mt < 4; ++mt)
        #pragma unroll
        for (int r = 0; r < 4; ++r) {
            int p = mt * 4 + r;
            unsigned b1 = 0xFFFFFFFFu, b2v = 0xFFFFFFFFu;
            #pragma unroll
            for (int nt = 0; nt < 4; ++nt) {
                float dist = fmaf(-2.f, acc[mt][nt][r], cv[nt]);
                unsigned u = (unsigned)fmaf(dist, 32768.f, 4194304.f); // (d+128)*2^15
                unsigned key = (u << 8) | (unsigned)(w * 64 + nt * 16 + l15);
                unsigned t = key > b1 ? key : b1;    // max
                b1 = key < b1 ? key : b1;            // min
                b2v = t < b2v ? t : b2v;             // min
            }
            m1[p] = b1; m2[p] = b2v;
        }
    #pragma unroll
    for (int s = 1; s < 16; s <<= 1) {
        #pragma unroll
        for (int p = 0; p < 16; ++p) {
            unsigned n1 = (unsigned)__shfl_xor((int)m1[p], s);
            unsigned n2 = (unsigned)__shfl_xor((int)m2[p], s);
            unsigned t = m1[p] > n1 ? m1[p] : n1;
            m1[p] = m1[p] < n1 ? m1[p] : n1;
            unsigned mn = n2 < t ? n2 : t;
            m2[p] = m2[p] < mn ? m2[p] : mn;         // min3(m2, n2, t)
        }
    }
    if (l15 == 0) {
        #pragma unroll
        for (int mt = 0; mt < 4; ++mt)
            #pragma unroll
            for (int r = 0; r < 4; ++r) {
                int p = mt * 4 + r;
                int t = mt * 16 + lq * 4 + r;
                red1[t * 5 + w] = m1[p]; red2[t * 5 + w] = m2[p];
            }
    }
    __syncthreads();
    if (tid < 64) {   // order-independent min/max merge: deterministic
        unsigned a1 = red1[tid * 5], a2v = red2[tid * 5];
        #pragma unroll
        for (int q = 1; q < 4; ++q) {
            unsigned n1 = red1[tid * 5 + q], n2 = red2[tid * 5 + q];
            unsigned t = a1 > n1 ? a1 : n1;
            a1 = a1 < n1 ? a1 : n1;
            unsigned mn = n2 < t ? n2 : t;
            a2v = a2v < mn ? a2v : mn;
        }
        size_t o = (size_t)nb * N_ + n0 + tid;
        pd1[o] = (float)(a1 >> 8) * (1.f / 32768.f) - 128.f;
        pi1[o] = k0 + (int)(a1 & 255u);
        pd2[o] = (float)(a2v >> 8) * (1.f / 32768.f) - 128.f;
    }
}

// ---------------- merge 32 blocks; enumerate pair/scan candidates -----------
// counters[0]=pairs, [1]=block-scan tasks. Coverage: true winner j in block B
// is B's top-1 (pd1<=W -> pair) or has obs >= pd2_B, forcing pd2_B<=W -> B
// gets an exact 256-code scan which covers ANY rank in B.
__global__ __launch_bounds__(256)
void merge_flag(const float* __restrict__ pd1, const int* __restrict__ pi1,
                const float* __restrict__ pd2,
                int* __restrict__ idx, int* __restrict__ counters,
                unsigned long long* __restrict__ key,
                unsigned int* __restrict__ pairs, unsigned int* __restrict__ scans) {
    int n = blockIdx.x * 256 + threadIdx.x;
    float a = 3.4e38f, b2 = 3.4e38f; int ai = -1;
    for (int nb = 0; nb < NB_; ++nb) {
        float n1 = pd1[(size_t)nb * N_ + n];
        int   ni = pi1[(size_t)nb * N_ + n];
        float n2 = pd2[(size_t)nb * N_ + n];
        if (n1 < a) { b2 = fminf(a, n2); a = n1; ai = ni; }
        else        { b2 = fminf(b2, n1); }
    }
    if (b2 - a < MARGIN) {
        const float W = a + MARGIN;
        key[n] = ~0ULL;
        idx[n] = 0x80000000 | ai;          // flagged: resolve from key later
        for (int nb = 0; nb < NB_; ++nb) {
            if (pd2[(size_t)nb * N_ + n] <= W) {
                int q = atomicAdd(&counters[1], 1);
                scans[q] = ((unsigned)n << 5) | (unsigned)nb;
            } else if (pd1[(size_t)nb * N_ + n] <= W) {
                int q = atomicAdd(&counters[0], 1);
                pairs[q] = ((unsigned)n << 13) | (unsigned)pi1[(size_t)nb * N_ + n];
            }
        }
    } else {
        idx[n] = ai;
    }
}

// ---------------- fused exact fp32 recheck (pairs + block scans) ------------
// blocks [0,128): 4 threads per (token, candidate); blocks [128,384): one
// (token, 256-code block) exact scan per task, E rows coalesced.
__global__ __launch_bounds__(256)
void recheck(const float* __restrict__ x, const float* __restrict__ E,
             const float* __restrict__ c, const unsigned int* __restrict__ pairs,
             const unsigned int* __restrict__ scans, const int* __restrict__ counters,
             unsigned long long* __restrict__ key) {
    if (blockIdx.x < 128) {
        int items = counters[0] * 4;
        for (int it = blockIdx.x * 256 + threadIdx.x; it < items; it += 128 * 256) {
            int p = it >> 2, q = it & 3;   // quads stay intact: stride % 4 == 0
            unsigned v = pairs[p];
            int n = v >> 13, k = v & 8191;
            int b = n >> 10, s = n & 1023;
            const float* xb = x + (size_t)b * 262144 + s;
            const float* eb = E + k;
            float acc = 0.f;
            const int d0 = q * 64;
            #pragma unroll 8
            for (int d = d0; d < d0 + 64; ++d)
                acc = fmaf(xb[(size_t)d * HW_], eb[(size_t)d * K_], acc);
            float o1 = __shfl_xor(acc, 1); float s2 = acc + o1;
            float o2 = __shfl_xor(s2, 2);  float tot = s2 + o2;   // ((q0+q1)+(q2+q3))
            if (q == 0) atomicMin(key + n, pack_dk(fmaf(-2.f, tot, c[k]), k));
        }
    } else {
        int cnt = counters[1];
        for (int t = blockIdx.x - 128; t < cnt; t += 256) {
            unsigned v = scans[t];
            int n = v >> 5, nb = v & 31;
            int k = nb * 256 + threadIdx.x;
            int b = n >> 10, s = n & 1023;
            const float* xb = x + (size_t)b * 262144 + s;
            float acc = 0.f;
            #pragma unroll 4
            for (int d = 0; d < D_; ++d)          // ascending d: exact ref chain
                acc = fmaf(xb[(size_t)d * HW_], E[(size_t)d * K_ + k], acc);
            float dist = fmaf(-2.f, acc, c[k]);
            atomicMin(key + n, pack_dk(dist, k));  // (dist,k) lex-min: first-min ties
        }
    }
}

// ---------------- gather + write outputs (float4, fixup via sign bit) -------
// grid (256, 4): blockIdx.y selects a 64-d band -> 4 blocks/CU (was 1,
// latency-bound gather).
__global__ __launch_bounds__(256)
void write_kernel(const float* __restrict__ x, const float* __restrict__ E,
                  const int* __restrict__ idx, const unsigned long long* __restrict__ key,
                  float* __restrict__ out) {
    __shared__ int kst[64];
    const int n0 = blockIdx.x * 64;
    const int b = n0 >> 10, s0 = n0 & 1023;
    const int tid = threadIdx.x;
    if (tid < 64) {
        int v = idx[n0 + tid];
        int k = (v < 0) ? (int)(key[n0 + tid] & 8191ULL) : v;
        kst[tid] = k;
        if (blockIdx.y == 0) out[IND_OFF + n0 + tid] = (float)k;
    }
    __syncthreads();
    const int g = tid & 15;               // float4 group of 4 tokens
    const int d0 = tid >> 4;              // 16 d-streams
    const int dband = blockIdx.y * 64;    // this block's 64-d band
    const int ka = kst[g * 4], kb2 = kst[g * 4 + 1], kc = kst[g * 4 + 2], kd = kst[g * 4 + 3];
    const float* xb = x + (size_t)b * 262144 + s0 + g * 4;
    float* o0 = out + (size_t)b * 262144 + s0 + g * 4;
    float* o1 = o0 + OUT1_OFF;
    for (int d = dband + d0; d < dband + 64; d += 16) {
        const float* er = E + (size_t)d * K_;
        float4 xv = *(const float4*)(xb + (size_t)d * HW_);
        float4 q;
        q.x = er[ka]; q.y = er[kb2]; q.z = er[kc]; q.w = er[kd];
        float4 r;                          // x + (q - x): replicate jnp fp32 rounding
        r.x = xv.x + (q.x - xv.x); r.y = xv.y + (q.y - xv.y);
        r.z = xv.z + (q.z - xv.z); r.w = xv.w + (q.w - xv.w);
        *(float4*)(o0 + (size_t)d * HW_) = r;
        *(float4*)(o1 + (size_t)d * HW_) = q;
    }
}

extern "C" void kernel_launch(void* const* d_in, const int* in_sizes, int n_in,
                              void* d_out, int out_size, void* d_ws, size_t ws_size,
                              hipStream_t stream) {
    const float* x = (const float*)d_in[0];
    const float* E = (const float*)d_in[1];
    float* out = (float*)d_out;

    char* p = (char*)d_ws;
    ushort* xf = (ushort*)p;                 p += (size_t)N_ * D_ * 2;   // 8 MB
    ushort* ef = (ushort*)p;                 p += (size_t)K_ * D_ * 2;   // 4 MB
    float*  c  = (float*)p;                  p += (size_t)K_ * 4;
    float*  pd1 = (float*)p;                 p += (size_t)NB_ * N_ * 4;  // 2 MB
    int*    pi1 = (int*)p;                   p += (size_t)NB_ * N_ * 4;
    float*  pd2 = (float*)p;                 p += (size_t)NB_ * N_ * 4;
    int*    idx = (int*)p;                   p += (size_t)N_ * 4;
    unsigned long long* key = (unsigned long long*)p; p += (size_t)N_ * 8;
    unsigned int* pairs = (unsigned int*)p;  p += (size_t)524288 * 4;    // 2 MB cap
    unsigned int* scans = (unsigned int*)p;  p += (size_t)524288 * 4;    // 2 MB cap
    int*    counters = (int*)p;              p += 256;

    cnorm_kernel<<<K_ / 32, 256, 0, stream>>>(E, c, counters);
    prep_x<<<dim3(32, 8, 16), 256, 0, stream>>>(x, xf);
    prep_e<<<dim3(256, 8), 256, 0, stream>>>(E, ef);
    mfma_kernel<<<8192, 256, 0, stream>>>(xf, ef, c, pd1, pi1, pd2);
    merge_flag<<<N_ / 256, 256, 0, stream>>>(pd1, pi1, pd2, idx, counters, key, pairs, scans);
    recheck<<<384, 256, 0, stream>>>(x, E, c, pairs, scans, counters, key);
    write_kernel<<<dim3(256, 4), 256, 0, stream>>>(x, E, idx, key, out);
}

// Round 13
// 353.771 us; speedup vs baseline: 1.2377x; 1.0077x over previous
//
#include <hip/hip_runtime.h>
#include <hip/hip_bf16.h>
#include <hip/hip_fp16.h>

// VQ codebook lookup via fp16 MFMA + margin-based candidate recheck.
// x[16,256,32,32] f32, E[256,8192] f32, N=16384 tokens, K=8192 codes.
// S = fp16(x)·fp16(e) via mfma_f32_16x16x32_f16 (fp16 products exact in
// fp32): dist-err sigma ~7.8e-4, pairwise ~1.1e-3; MARGIN 0.02 ~ 18 sigma.
// Flagged tokens: block top-1s in window -> exact pair recheck; blocks with
// top-2 in window -> exact 256-code BLOCK scan. Exact path = ascending-d
// fmaf chain (validated R1-R8).
//
// R22 = R19 with the block tile fattened to 128 tok x 256 codes (R11's
//   absmax-0 geometry: 4 waves 2x2, wave tile 64x128, acc[4][8]):
//   R19/R21 accounting: wall ~1356 cy/step == 3 blocks x 52 KB LDS traffic
//   / 128 B/cy -> the CU-level LDS PORT is the binding pipe. Fat tile cuts
//   LDS bytes per output 52 -> 36 KB (staged 24 + read 48 for 2x output);
//   grid 8192 -> 4096. LDS = A dbuf 16 + B dbuf 32 + red 3 = 51 KB ->
//   still 3 blocks/CU.
//   Kept (validated): fp16 single-pass (R14), 2-phase gload_lds dbuf
//   __syncthreads loop (R14/R19 — R17/R20/R21 proved direct-global loads
//   lose their prefetch distance), XOR staging swizzle (R6/R7), packed-u32
//   top-2 epilogue + 4-way write split (R17/R19), XCD both-operand L2
//   residency (xcd owns mb [xcd*16,+16), nb slow; FETCH ~21MB).
// Downstream kernels and pd1/pi1/pd2 layout unchanged from R19 (absmax 0).

#define D_   256
#define HW_  1024
#define N_   16384
#define K_   8192
#define NB_  32              // 32 code-blocks of 256
#define MARGIN 0.02f         // ~18 sigma of fp16 approx-error difference

#define OUT1_OFF 4194304     // B*D*H*W
#define IND_OFF  8388608

typedef __attribute__((ext_vector_type(8))) _Float16 f16x8;  // 8 f16 = 4 VGPR
typedef __attribute__((ext_vector_type(4))) float f32x4;

__device__ __forceinline__ unsigned long long pack_dk(float dist, int k) {
    unsigned db = __float_as_uint(dist);
    unsigned mono = (db & 0x80000000u) ? ~db : (db | 0x80000000u);
    return ((unsigned long long)mono << 32) | (unsigned)k;
}

// async global->LDS DMA: lane i of the wave lands at ldsbase + 16*i.
__device__ __forceinline__ void async_copy16(const void* g, void* l) {
    __builtin_amdgcn_global_load_lds(
        (const __attribute__((address_space(1))) void*)g,
        (__attribute__((address_space(3))) void*)l, 16, 0, 0);
}

// ---------------- codebook column norms + counter zeroing -------------------
__global__ __launch_bounds__(256)
void cnorm_kernel(const float* __restrict__ E, float* __restrict__ c,
                  int* __restrict__ counters) {
    if (blockIdx.x == 0 && threadIdx.x < 2) counters[threadIdx.x] = 0;
    __shared__ float part[8][32];
    const int tid = threadIdx.x;
    const int cl = tid & 31, q = tid >> 5;
    const int k = blockIdx.x * 32 + cl;
    float s = 0.f;
    #pragma unroll 8
    for (int d = q * 32; d < q * 32 + 32; ++d) {
        float v = E[(size_t)d * K_ + k];
        s = fmaf(v, v, s);
    }
    part[q][cl] = s;
    __syncthreads();
    if (tid < 32) {   // fixed combine order: deterministic
        float t0 = (part[0][tid] + part[1][tid]) + (part[2][tid] + part[3][tid]);
        float t1 = (part[4][tid] + part[5][tid]) + (part[6][tid] + part[7][tid]);
        c[blockIdx.x * 32 + tid] = t0 + t1;
    }
}

// ---------------- prep: x fp32 -> fp16 plane, transposed to token-major -----
__global__ __launch_bounds__(256)
void prep_x(const float* __restrict__ x, ushort* __restrict__ xf) {
    __shared__ float t[32][33];
    const int s0 = blockIdx.x * 32, d0 = blockIdx.y * 32, b = blockIdx.z;
    const int tid = threadIdx.x;
    #pragma unroll
    for (int j = 0; j < 4; ++j) {
        int i = tid + 256 * j; int dd = i >> 5, ss = i & 31;
        t[dd][ss] = x[(size_t)b * 262144 + (size_t)(d0 + dd) * 1024 + s0 + ss];
    }
    __syncthreads();
    #pragma unroll
    for (int j = 0; j < 4; ++j) {
        int i = tid + 256 * j; int ss = i >> 5, dd = i & 31;
        _Float16 h = (_Float16)t[dd][ss];          // RN f32->f16
        size_t o = (size_t)(b * 1024 + s0 + ss) * D_ + d0 + dd;
        xf[o] = *(ushort*)&h;
    }
}

// E[d][k] -> ef[k][d] fp16
__global__ __launch_bounds__(256)
void prep_e(const float* __restrict__ E, ushort* __restrict__ ef) {
    __shared__ float t[32][33];
    const int k0 = blockIdx.x * 32, d0 = blockIdx.y * 32;
    const int tid = threadIdx.x;
    #pragma unroll
    for (int j = 0; j < 4; ++j) {
        int i = tid + 256 * j; int dd = i >> 5, kk = i & 31;
        t[dd][kk] = E[(size_t)(d0 + dd) * K_ + k0 + kk];
    }
    __syncthreads();
    #pragma unroll
    for (int j = 0; j < 4; ++j) {
        int i = tid + 256 * j; int kk = i >> 5, dd = i & 31;
        _Float16 h = (_Float16)t[dd][kk];
        ef[(size_t)(k0 + kk) * D_ + d0 + dd] = *(ushort*)&h;
    }
}

// ---------------- MFMA distance + per-token top-2 per 256-code block --------
// grid 4096 flat, XCD-partitioned. block 256 = 4 waves (2x2), block tile
// 128 tokens x 256 codes, wave tile 64x128 (acc[4][8]). 2-phase dbuf,
// prefetch t+1 before compute of t, one __syncthreads per step. LDS rows =
// 64B of 4x16B chunks, chunk position = chunk ^ ((row>>1)&3) — conflict-free
// (R6/R7/R11-verified). Packed-u32 top-2 epilogue (R17/R19-validated).
__global__ __launch_bounds__(256, 3)
void mfma_kernel(const ushort* __restrict__ xf,
                 const ushort* __restrict__ ef,
                 const float* __restrict__ c,
                 float* __restrict__ pd1, int* __restrict__ pi1, float* __restrict__ pd2) {
    __shared__ __align__(16) ushort Af[2][4096];   // [2][128*32] 16 KB
    __shared__ __align__(16) ushort Bf[2][8192];   // [2][256*32] 32 KB
    __shared__ unsigned red1[384], red2[384];      // [128][3] stride-3: conflict-free

    const int tid = threadIdx.x;
    // XCD partition: xcd owns mb in [xcd*16, xcd*16+16); nb slow within xcd.
    const int bid = blockIdx.x;
    const int xcd = bid & 7, rr = bid >> 3;        // rr in [0,512)
    const int nb = rr >> 4, mb = xcd * 16 + (rr & 15);
    const int n0 = mb * 128, k0 = nb * 256;
    const int lane = tid & 63, w = tid >> 6;
    const int wy = w >> 1, wx = w & 1;             // 2x2 wave layout
    const int l15 = lane & 15, lq = lane >> 4;

    // A staging: 2 gload_lds per wave per step (4 waves cover 128 rows)
    size_t aoff[2]; int adst[2];
    #pragma unroll
    for (int g = 0; g < 2; ++g) {
        int slot = (w * 2 + g) * 64 + lane;
        int t = slot >> 2, cp = slot & 3;
        int cs = cp ^ ((t >> 1) & 3);
        aoff[g] = (size_t)(n0 + t) * D_ + cs * 8;
        adst[g] = (w * 2 + g) * 512;
    }
    // B staging: 4 gload_lds per wave per step
    size_t boff[4]; int bdst[4];
    #pragma unroll
    for (int g = 0; g < 4; ++g) {
        int slot = (w * 4 + g) * 64 + lane;
        int t = slot >> 2, cp = slot & 3;
        int cs = cp ^ ((t >> 1) & 3);
        boff[g] = (size_t)(k0 + t) * D_ + cs * 8;
        bdst[g] = (w * 4 + g) * 512;
    }
    // fragment read offsets (XOR matches staging swizzle)
    int aro[4], bro[8];
    #pragma unroll
    for (int mt = 0; mt < 4; ++mt) {
        int R = wy * 64 + mt * 16 + l15;
        aro[mt] = R * 32 + ((lq ^ ((R >> 1) & 3)) * 8);
    }
    #pragma unroll
    for (int nt = 0; nt < 8; ++nt) {
        int R = wx * 128 + nt * 16 + l15;
        bro[nt] = R * 32 + ((lq ^ ((R >> 1) & 3)) * 8);
    }

    f32x4 acc[4][8];
    #pragma unroll
    for (int mt = 0; mt < 4; ++mt)
        #pragma unroll
        for (int nt = 0; nt < 8; ++nt) acc[mt][nt] = (f32x4){0.f, 0.f, 0.f, 0.f};

    // prologue: stage step 0 into buffer 0
    #pragma unroll
    for (int g = 0; g < 2; ++g)
        async_copy16(xf + aoff[g], &Af[0][adst[g]]);
    #pragma unroll
    for (int g = 0; g < 4; ++g)
        async_copy16(ef + boff[g], &Bf[0][bdst[g]]);
    __syncthreads();

    #pragma unroll
    for (int db = 0; db < 8; ++db) {
        const int cur = db & 1;
        const int d0 = db * 32;
        if (db < 7) {   // prefetch step t+1 into the other buffer
            const int dn = d0 + 32;
            #pragma unroll
            for (int g = 0; g < 2; ++g)
                async_copy16(xf + aoff[g] + dn, &Af[cur ^ 1][adst[g]]);
            #pragma unroll
            for (int g = 0; g < 4; ++g)
                async_copy16(ef + boff[g] + dn, &Bf[cur ^ 1][bdst[g]]);
        }
        f16x8 a[4];
        #pragma unroll
        for (int mt = 0; mt < 4; ++mt)
            a[mt] = *(const f16x8*)&Af[cur][aro[mt]];
        #pragma unroll
        for (int nt = 0; nt < 8; ++nt) {
            f16x8 b = *(const f16x8*)&Bf[cur][bro[nt]];
            #pragma unroll
            for (int mt = 0; mt < 4; ++mt)
                acc[mt][nt] = __builtin_amdgcn_mfma_f32_16x16x32_f16(a[mt], b, acc[mt][nt], 0, 0, 0);
        }
        __syncthreads();   // drains prefetch; protects buffer reuse
    }

    float cv[8];
    #pragma unroll
    for (int nt = 0; nt < 8; ++nt) cv[nt] = c[k0 + wx * 128 + nt * 16 + l15];

    // packed top-2: key = ((uint)((dist+128)*2^15) << 8) | code8.
    // dist bounded |dist| <= 1+2*||x||·||e|| < 40 << 128; quant step ~8e-6
    // absorbed by MARGIN (18 sigma). min = dist asc then code asc
    // (= first-min ties). R17/R19-validated (absmax 0).
    unsigned m1[16], m2[16];
    #pragma unroll
    for (int mt = 0; mt < 4; ++mt)
        #pragma unroll
        for (int r = 0; r < 4; ++r) {
            int p = mt * 4 + r;
            unsigned b1 = 0xFFFFFFFFu, b2v = 0xFFFFFFFFu;
            #pragma unroll
            for (int nt = 0; nt < 8; ++nt) {
                float dist = fmaf(-2.f, acc[mt][nt][r], cv[nt]);
                unsigned u = (unsigned)fmaf(dist, 32768.f, 4194304.f); // (d+128)*2^15
                unsigned key = (u << 8) | (unsigned)(wx * 128 + nt * 16 + l15);
                unsigned t = key > b1 ? key : b1;    // max
                b1 = key < b1 ? key : b1;            // min
                b2v = t < b2v ? t : b2v;             // min
            }
            m1[p] = b1; m2[p] = b2v;
        }
    #pragma unroll
    for (int s = 1; s < 16; s <<= 1) {
        #pragma unroll
        for (int p = 0; p < 16; ++p) {
            unsigned n1 = (unsigned)__shfl_xor((int)m1[p], s);
            unsigned n2 = (unsigned)__shfl_xor((int)m2[p], s);
            unsigned t = m1[p] > n1 ? m1[p] : n1;
            m1[p] = m1[p] < n1 ? m1[p] : n1;
            unsigned mn = n2 < t ? n2 : t;
            m2[p] = m2[p] < mn ? m2[p] : mn;         // min3(m2, n2, t)
        }
    }
    if (l15 == 0) {
        #pragma unroll
        for (int mt = 0; mt < 4; ++mt)
            #pragma unroll
            for (int r = 0; r < 4; ++r) {
                int p = mt * 4 + r;
                int t = wy * 64 + mt * 16 + lq * 4 + r;   // token 0..127
                red1[t * 3 + wx] = m1[p]; red2[t * 3 + wx] = m2[p];
            }
    }
    __syncthreads();
    if (tid < 128) {   // order-independent min/max merge: deterministic
        unsigned a1 = red1[tid * 3], a2v = red2[tid * 3];
        unsigned n1 = red1[tid * 3 + 1], n2 = red2[tid * 3 + 1];
        unsigned t = a1 > n1 ? a1 : n1;
        a1 = a1 < n1 ? a1 : n1;
        unsigned mn = n2 < t ? n2 : t;
        a2v = a2v < mn ? a2v : mn;
        size_t o = (size_t)nb * N_ + n0 + tid;
        pd1[o] = (float)(a1 >> 8) * (1.f / 32768.f) - 128.f;
        pi1[o] = k0 + (int)(a1 & 255u);
        pd2[o] = (float)(a2v >> 8) * (1.f / 32768.f) - 128.f;
    }
}

// ---------------- merge 32 blocks; enumerate pair/scan candidates -----------
// counters[0]=pairs, [1]=block-scan tasks. Coverage: true winner j in block B
// is B's top-1 (pd1<=W -> pair) or has obs >= pd2_B, forcing pd2_B<=W -> B
// gets an exact 256-code scan which covers ANY rank in B.
__global__ __launch_bounds__(256)
void merge_flag(const float* __restrict__ pd1, const int* __restrict__ pi1,
                const float* __restrict__ pd2,
                int* __restrict__ idx, int* __restrict__ counters,
                unsigned long long* __restrict__ key,
                unsigned int* __restrict__ pairs, unsigned int* __restrict__ scans) {
    int n = blockIdx.x * 256 + threadIdx.x;
    float a = 3.4e38f, b2 = 3.4e38f; int ai = -1;
    for (int nb = 0; nb < NB_; ++nb) {
        float n1 = pd1[(size_t)nb * N_ + n];
        int   ni = pi1[(size_t)nb * N_ + n];
        float n2 = pd2[(size_t)nb * N_ + n];
        if (n1 < a) { b2 = fminf(a, n2); a = n1; ai = ni; }
        else        { b2 = fminf(b2, n1); }
    }
    if (b2 - a < MARGIN) {
        const float W = a + MARGIN;
        key[n] = ~0ULL;
        idx[n] = 0x80000000 | ai;          // flagged: resolve from key later
        for (int nb = 0; nb < NB_; ++nb) {
            if (pd2[(size_t)nb * N_ + n] <= W) {
                int q = atomicAdd(&counters[1], 1);
                scans[q] = ((unsigned)n << 5) | (unsigned)nb;
            } else if (pd1[(size_t)nb * N_ + n] <= W) {
                int q = atomicAdd(&counters[0], 1);
                pairs[q] = ((unsigned)n << 13) | (unsigned)pi1[(size_t)nb * N_ + n];
            }
        }
    } else {
        idx[n] = ai;
    }
}

// ---------------- fused exact fp32 recheck (pairs + block scans) ------------
// blocks [0,128): 4 threads per (token, candidate); blocks [128,384): one
// (token, 256-code block) exact scan per task, E rows coalesced.
__global__ __launch_bounds__(256)
void recheck(const float* __restrict__ x, const float* __restrict__ E,
             const float* __restrict__ c, const unsigned int* __restrict__ pairs,
             const unsigned int* __restrict__ scans, const int* __restrict__ counters,
             unsigned long long* __restrict__ key) {
    if (blockIdx.x < 128) {
        int items = counters[0] * 4;
        for (int it = blockIdx.x * 256 + threadIdx.x; it < items; it += 128 * 256) {
            int p = it >> 2, q = it & 3;   // quads stay intact: stride % 4 == 0
            unsigned v = pairs[p];
            int n = v >> 13, k = v & 8191;
            int b = n >> 10, s = n & 1023;
            const float* xb = x + (size_t)b * 262144 + s;
            const float* eb = E + k;
            float acc = 0.f;
            const int d0 = q * 64;
            #pragma unroll 8
            for (int d = d0; d < d0 + 64; ++d)
                acc = fmaf(xb[(size_t)d * HW_], eb[(size_t)d * K_], acc);
            float o1 = __shfl_xor(acc, 1); float s2 = acc + o1;
            float o2 = __shfl_xor(s2, 2);  float tot = s2 + o2;   // ((q0+q1)+(q2+q3))
            if (q == 0) atomicMin(key + n, pack_dk(fmaf(-2.f, tot, c[k]), k));
        }
    } else {
        int cnt = counters[1];
        for (int t = blockIdx.x - 128; t < cnt; t += 256) {
            unsigned v = scans[t];
            int n = v >> 5, nb = v & 31;
            int k = nb * 256 + threadIdx.x;
            int b = n >> 10, s = n & 1023;
            const float* xb = x + (size_t)b * 262144 + s;
            float acc = 0.f;
            #pragma unroll 4
            for (int d = 0; d < D_; ++d)          // ascending d: exact ref chain
                acc = fmaf(xb[(size_t)d * HW_], E[(size_t)d * K_ + k], acc);
            float dist = fmaf(-2.f, acc, c[k]);
            atomicMin(key + n, pack_dk(dist, k));  // (dist,k) lex-min: first-min ties
        }
    }
}

// ---------------- gather + write outputs (float4, fixup via sign bit) -------
// grid (256, 4): blockIdx.y selects a 64-d band -> 4 blocks/CU (was 1,
// latency-bound gather).
__global__ __launch_bounds__(256)
void write_kernel(const float* __restrict__ x, const float* __restrict__ E,
                  const int* __restrict__ idx, const unsigned long long* __restrict__ key,
                  float* __restrict__ out) {
    __shared__ int kst[64];
    const int n0 = blockIdx.x * 64;
    const int b = n0 >> 10, s0 = n0 & 1023;
    const int tid = threadIdx.x;
    if (tid < 64) {
        int v = idx[n0 + tid];
        int k = (v < 0) ? (int)(key[n0 + tid] & 8191ULL) : v;
        kst[tid] = k;
        if (blockIdx.y == 0) out[IND_OFF + n0 + tid] = (float)k;
    }
    __syncthreads();
    const int g = tid & 15;               // float4 group of 4 tokens
    const int d0 = tid >> 4;              // 16 d-streams
    const int dband = blockIdx.y * 64;    // this block's 64-d band
    const int ka = kst[g * 4], kb2 = kst[g * 4 + 1], kc = kst[g * 4 + 2], kd = kst[g * 4 + 3];
    const float* xb = x + (size_t)b * 262144 + s0 + g * 4;
    float* o0 = out + (size_t)b * 262144 + s0 + g * 4;
    float* o1 = o0 + OUT1_OFF;
    for (int d = dband + d0; d < dband + 64; d += 16) {
        const float* er = E + (size_t)d * K_;
        float4 xv = *(const float4*)(xb + (size_t)d * HW_);
        float4 q;
        q.x = er[ka]; q.y = er[kb2]; q.z = er[kc]; q.w = er[kd];
        float4 r;                          // x + (q - x): replicate jnp fp32 rounding
        r.x = xv.x + (q.x - xv.x); r.y = xv.y + (q.y - xv.y);
        r.z = xv.z + (q.z - xv.z); r.w = xv.w + (q.w - xv.w);
        *(float4*)(o0 + (size_t)d * HW_) = r;
        *(float4*)(o1 + (size_t)d * HW_) = q;
    }
}

extern "C" void kernel_launch(void* const* d_in, const int* in_sizes, int n_in,
                              void* d_out, int out_size, void* d_ws, size_t ws_size,
                              hipStream_t stream) {
    const float* x = (const float*)d_in[0];
    const float* E = (const float*)d_in[1];
    float* out = (float*)d_out;

    char* p = (char*)d_ws;
    ushort* xf = (ushort*)p;                 p += (size_t)N_ * D_ * 2;   // 8 MB
    ushort* ef = (ushort*)p;                 p += (size_t)K_ * D_ * 2;   // 4 MB
    float*  c  = (float*)p;                  p += (size_t)K_ * 4;
    float*  pd1 = (float*)p;                 p += (size_t)NB_ * N_ * 4;  // 2 MB
    int*    pi1 = (int*)p;                   p += (size_t)NB_ * N_ * 4;
    float*  pd2 = (float*)p;                 p += (size_t)NB_ * N_ * 4;
    int*    idx = (int*)p;                   p += (size_t)N_ * 4;
    unsigned long long* key = (unsigned long long*)p; p += (size_t)N_ * 8;
    unsigned int* pairs = (unsigned int*)p;  p += (size_t)524288 * 4;    // 2 MB cap
    unsigned int* scans = (unsigned int*)p;  p += (size_t)524288 * 4;    // 2 MB cap
    int*    counters = (int*)p;              p += 256;

    cnorm_kernel<<<K_ / 32, 256, 0, stream>>>(E, c, counters);
    prep_x<<<dim3(32, 8, 16), 256, 0, stream>>>(x, xf);
    prep_e<<<dim3(256, 8), 256, 0, stream>>>(E, ef);
    mfma_kernel<<<4096, 256, 0, stream>>>(xf, ef, c, pd1, pi1, pd2);
    merge_flag<<<N_ / 256, 256, 0, stream>>>(pd1, pi1, pd2, idx, counters, key, pairs, scans);
    recheck<<<384, 256, 0, stream>>>(x, E, c, pairs, scans, counters, key);
    write_kernel<<<dim3(256, 4), 256, 0, stream>>>(x, E, idx, key, out);
}

// Round 14
// 299.577 us; speedup vs baseline: 1.4617x; 1.1809x over previous
//
#include <hip/hip_runtime.h>
#include <hip/hip_bf16.h>
#include <hip/hip_fp16.h>

// VQ codebook lookup via fp16 MFMA + margin-based candidate recheck.
// x[16,256,32,32] f32, E[256,8192] f32, N=16384 tokens, K=8192 codes.
// S = fp16(x)·fp16(e) via mfma_f32_16x16x32_f16 (fp16 products exact in
// fp32): dist-err sigma ~7.8e-4, pairwise ~1.1e-3; MARGIN 0.02 ~ 18 sigma.
// Flagged tokens: block top-1s in window -> exact pair recheck; blocks with
// top-2 in window -> exact 256-code BLOCK scan. Exact path = ascending-d
// fmaf chain (validated R1-R8).
//
// R23 = R22 with __launch_bounds__(256, 2) — spill fix.
//   R22 post-mortem: launch_bounds(256,3) capped regs at ~170 while the
//   128x256 tile needs ~200 (acc[4][8]=128) -> compiler SPILLED the
//   accumulators: WRITE_SIZE 6->255MB, FETCH 21->150MB, VGPR_Count 84,
//   HBM-bound at 164us. (256,2) lifts the cap (R11 precedent: same
//   geometry, VGPR 124, WRITE 6MB, absmax 0). 2 blocks/CU: LDS-port gives
//   2x72KB/128B ~ 1150 cy per step-slot for 1.33x R19's output -> ~1.4x
//   LDS-port efficiency vs R19's 52KB/output, if 2 barrier domains give
//   enough latency cover.
//   Kept (validated): fp16 single-pass (R14), 2-phase gload_lds dbuf
//   __syncthreads loop (R14/R19), XOR staging swizzle (R6/R7/R11),
//   packed-u32 top-2 epilogue + 4-way write split (R17/R19), XCD
//   both-operand L2 residency (xcd owns mb [xcd*16,+16), nb slow).
// Downstream kernels and pd1/pi1/pd2 layout unchanged from R19 (absmax 0).

#define D_   256
#define HW_  1024
#define N_   16384
#define K_   8192
#define NB_  32              // 32 code-blocks of 256
#define MARGIN 0.02f         // ~18 sigma of fp16 approx-error difference

#define OUT1_OFF 4194304     // B*D*H*W
#define IND_OFF  8388608

typedef __attribute__((ext_vector_type(8))) _Float16 f16x8;  // 8 f16 = 4 VGPR
typedef __attribute__((ext_vector_type(4))) float f32x4;

__device__ __forceinline__ unsigned long long pack_dk(float dist, int k) {
    unsigned db = __float_as_uint(dist);
    unsigned mono = (db & 0x80000000u) ? ~db : (db | 0x80000000u);
    return ((unsigned long long)mono << 32) | (unsigned)k;
}

// async global->LDS DMA: lane i of the wave lands at ldsbase + 16*i.
__device__ __forceinline__ void async_copy16(const void* g, void* l) {
    __builtin_amdgcn_global_load_lds(
        (const __attribute__((address_space(1))) void*)g,
        (__attribute__((address_space(3))) void*)l, 16, 0, 0);
}

// ---------------- codebook column norms + counter zeroing -------------------
__global__ __launch_bounds__(256)
void cnorm_kernel(const float* __restrict__ E, float* __restrict__ c,
                  int* __restrict__ counters) {
    if (blockIdx.x == 0 && threadIdx.x < 2) counters[threadIdx.x] = 0;
    __shared__ float part[8][32];
    const int tid = threadIdx.x;
    const int cl = tid & 31, q = tid >> 5;
    const int k = blockIdx.x * 32 + cl;
    float s = 0.f;
    #pragma unroll 8
    for (int d = q * 32; d < q * 32 + 32; ++d) {
        float v = E[(size_t)d * K_ + k];
        s = fmaf(v, v, s);
    }
    part[q][cl] = s;
    __syncthreads();
    if (tid < 32) {   // fixed combine order: deterministic
        float t0 = (part[0][tid] + part[1][tid]) + (part[2][tid] + part[3][tid]);
        float t1 = (part[4][tid] + part[5][tid]) + (part[6][tid] + part[7][tid]);
        c[blockIdx.x * 32 + tid] = t0 + t1;
    }
}

// ---------------- prep: x fp32 -> fp16 plane, transposed to token-major -----
__global__ __launch_bounds__(256)
void prep_x(const float* __restrict__ x, ushort* __restrict__ xf) {
    __shared__ float t[32][33];
    const int s0 = blockIdx.x * 32, d0 = blockIdx.y * 32, b = blockIdx.z;
    const int tid = threadIdx.x;
    #pragma unroll
    for (int j = 0; j < 4; ++j) {
        int i = tid + 256 * j; int dd = i >> 5, ss = i & 31;
        t[dd][ss] = x[(size_t)b * 262144 + (size_t)(d0 + dd) * 1024 + s0 + ss];
    }
    __syncthreads();
    #pragma unroll
    for (int j = 0; j < 4; ++j) {
        int i = tid + 256 * j; int ss = i >> 5, dd = i & 31;
        _Float16 h = (_Float16)t[dd][ss];          // RN f32->f16
        size_t o = (size_t)(b * 1024 + s0 + ss) * D_ + d0 + dd;
        xf[o] = *(ushort*)&h;
    }
}

// E[d][k] -> ef[k][d] fp16
__global__ __launch_bounds__(256)
void prep_e(const float* __restrict__ E, ushort* __restrict__ ef) {
    __shared__ float t[32][33];
    const int k0 = blockIdx.x * 32, d0 = blockIdx.y * 32;
    const int tid = threadIdx.x;
    #pragma unroll
    for (int j = 0; j < 4; ++j) {
        int i = tid + 256 * j; int dd = i >> 5, kk = i & 31;
        t[dd][kk] = E[(size_t)(d0 + dd) * K_ + k0 + kk];
    }
    __syncthreads();
    #pragma unroll
    for (int j = 0; j < 4; ++j) {
        int i = tid + 256 * j; int kk = i >> 5, dd = i & 31;
        _Float16 h = (_Float16)t[dd][kk];
        ef[(size_t)(k0 + kk) * D_ + d0 + dd] = *(ushort*)&h;
    }
}

// ---------------- MFMA distance + per-token top-2 per 256-code block --------
// grid 4096 flat, XCD-partitioned. block 256 = 4 waves (2x2), block tile
// 128 tokens x 256 codes, wave tile 64x128 (acc[4][8]). 2-phase dbuf,
// prefetch t+1 before compute of t, one __syncthreads per step. LDS rows =
// 64B of 4x16B chunks, chunk position = chunk ^ ((row>>1)&3) — conflict-free
// (R6/R7/R11-verified). Packed-u32 top-2 epilogue (R17/R19-validated).
__global__ __launch_bounds__(256, 2)
void mfma_kernel(const ushort* __restrict__ xf,
                 const ushort* __restrict__ ef,
                 const float* __restrict__ c,
                 float* __restrict__ pd1, int* __restrict__ pi1, float* __restrict__ pd2) {
    __shared__ __align__(16) ushort Af[2][4096];   // [2][128*32] 16 KB
    __shared__ __align__(16) ushort Bf[2][8192];   // [2][256*32] 32 KB
    __shared__ unsigned red1[384], red2[384];      // [128][3] stride-3: conflict-free

    const int tid = threadIdx.x;
    // XCD partition: xcd owns mb in [xcd*16, xcd*16+16); nb slow within xcd.
    const int bid = blockIdx.x;
    const int xcd = bid & 7, rr = bid >> 3;        // rr in [0,512)
    const int nb = rr >> 4, mb = xcd * 16 + (rr & 15);
    const int n0 = mb * 128, k0 = nb * 256;
    const int lane = tid & 63, w = tid >> 6;
    const int wy = w >> 1, wx = w & 1;             // 2x2 wave layout
    const int l15 = lane & 15, lq = lane >> 4;

    // A staging: 2 gload_lds per wave per step (4 waves cover 128 rows)
    size_t aoff[2]; int adst[2];
    #pragma unroll
    for (int g = 0; g < 2; ++g) {
        int slot = (w * 2 + g) * 64 + lane;
        int t = slot >> 2, cp = slot & 3;
        int cs = cp ^ ((t >> 1) & 3);
        aoff[g] = (size_t)(n0 + t) * D_ + cs * 8;
        adst[g] = (w * 2 + g) * 512;
    }
    // B staging: 4 gload_lds per wave per step
    size_t boff[4]; int bdst[4];
    #pragma unroll
    for (int g = 0; g < 4; ++g) {
        int slot = (w * 4 + g) * 64 + lane;
        int t = slot >> 2, cp = slot & 3;
        int cs = cp ^ ((t >> 1) & 3);
        boff[g] = (size_t)(k0 + t) * D_ + cs * 8;
        bdst[g] = (w * 4 + g) * 512;
    }
    // fragment read offsets (XOR matches staging swizzle)
    int aro[4], bro[8];
    #pragma unroll
    for (int mt = 0; mt < 4; ++mt) {
        int R = wy * 64 + mt * 16 + l15;
        aro[mt] = R * 32 + ((lq ^ ((R >> 1) & 3)) * 8);
    }
    #pragma unroll
    for (int nt = 0; nt < 8; ++nt) {
        int R = wx * 128 + nt * 16 + l15;
        bro[nt] = R * 32 + ((lq ^ ((R >> 1) & 3)) * 8);
    }

    f32x4 acc[4][8];
    #pragma unroll
    for (int mt = 0; mt < 4; ++mt)
        #pragma unroll
        for (int nt = 0; nt < 8; ++nt) acc[mt][nt] = (f32x4){0.f, 0.f, 0.f, 0.f};

    // prologue: stage step 0 into buffer 0
    #pragma unroll
    for (int g = 0; g < 2; ++g)
        async_copy16(xf + aoff[g], &Af[0][adst[g]]);
    #pragma unroll
    for (int g = 0; g < 4; ++g)
        async_copy16(ef + boff[g], &Bf[0][bdst[g]]);
    __syncthreads();

    #pragma unroll
    for (int db = 0; db < 8; ++db) {
        const int cur = db & 1;
        const int d0 = db * 32;
        if (db < 7) {   // prefetch step t+1 into the other buffer
            const int dn = d0 + 32;
            #pragma unroll
            for (int g = 0; g < 2; ++g)
                async_copy16(xf + aoff[g] + dn, &Af[cur ^ 1][adst[g]]);
            #pragma unroll
            for (int g = 0; g < 4; ++g)
                async_copy16(ef + boff[g] + dn, &Bf[cur ^ 1][bdst[g]]);
        }
        f16x8 a[4];
        #pragma unroll
        for (int mt = 0; mt < 4; ++mt)
            a[mt] = *(const f16x8*)&Af[cur][aro[mt]];
        #pragma unroll
        for (int nt = 0; nt < 8; ++nt) {
            f16x8 b = *(const f16x8*)&Bf[cur][bro[nt]];
            #pragma unroll
            for (int mt = 0; mt < 4; ++mt)
                acc[mt][nt] = __builtin_amdgcn_mfma_f32_16x16x32_f16(a[mt], b, acc[mt][nt], 0, 0, 0);
        }
        __syncthreads();   // drains prefetch; protects buffer reuse
    }

    float cv[8];
    #pragma unroll
    for (int nt = 0; nt < 8; ++nt) cv[nt] = c[k0 + wx * 128 + nt * 16 + l15];

    // packed top-2: key = ((uint)((dist+128)*2^15) << 8) | code8.
    // dist bounded |dist| <= 1+2*||x||·||e|| < 40 << 128; quant step ~8e-6
    // absorbed by MARGIN (18 sigma). min = dist asc then code asc
    // (= first-min ties). R17/R19-validated (absmax 0).
    unsigned m1[16], m2[16];
    #pragma unroll
    for (int mt = 0; mt < 4; ++mt)
        #pragma unroll
        for (int r = 0; r < 4; ++r) {
            int p = mt * 4 + r;
            unsigned b1 = 0xFFFFFFFFu, b2v = 0xFFFFFFFFu;
            #pragma unroll
            for (int nt = 0; nt < 8; ++nt) {
                float dist = fmaf(-2.f, acc[mt][nt][r], cv[nt]);
                unsigned u = (unsigned)fmaf(dist, 32768.f, 4194304.f); // (d+128)*2^15
                unsigned key = (u << 8) | (unsigned)(wx * 128 + nt * 16 + l15);
                unsigned t = key > b1 ? key : b1;    // max
                b1 = key < b1 ? key : b1;            // min
                b2v = t < b2v ? t : b2v;             // min
            }
            m1[p] = b1; m2[p] = b2v;
        }
    #pragma unroll
    for (int s = 1; s < 16; s <<= 1) {
        #pragma unroll
        for (int p = 0; p < 16; ++p) {
            unsigned n1 = (unsigned)__shfl_xor((int)m1[p], s);
            unsigned n2 = (unsigned)__shfl_xor((int)m2[p], s);
            unsigned t = m1[p] > n1 ? m1[p] : n1;
            m1[p] = m1[p] < n1 ? m1[p] : n1;
            unsigned mn = n2 < t ? n2 : t;
            m2[p] = m2[p] < mn ? m2[p] : mn;         // min3(m2, n2, t)
        }
    }
    if (l15 == 0) {
        #pragma unroll
        for (int mt = 0; mt < 4; ++mt)
            #pragma unroll
            for (int r = 0; r < 4; ++r) {
                int p = mt * 4 + r;
                int t = wy * 64 + mt * 16 + lq * 4 + r;   // token 0..127
                red1[t * 3 + wx] = m1[p]; red2[t * 3 + wx] = m2[p];
            }
    }
    __syncthreads();
    if (tid < 128) {   // order-independent min/max merge: deterministic
        unsigned a1 = red1[tid * 3], a2v = red2[tid * 3];
        unsigned n1 = red1[tid * 3 + 1], n2 = red2[tid * 3 + 1];
        unsigned t = a1 > n1 ? a1 : n1;
        a1 = a1 < n1 ? a1 : n1;
        unsigned mn = n2 < t ? n2 : t;
        a2v = a2v < mn ? a2v : mn;
        size_t o = (size_t)nb * N_ + n0 + tid;
        pd1[o] = (float)(a1 >> 8) * (1.f / 32768.f) - 128.f;
        pi1[o] = k0 + (int)(a1 & 255u);
        pd2[o] = (float)(a2v >> 8) * (1.f / 32768.f) - 128.f;
    }
}

// ---------------- merge 32 blocks; enumerate pair/scan candidates -----------
// counters[0]=pairs, [1]=block-scan tasks. Coverage: true winner j in block B
// is B's top-1 (pd1<=W -> pair) or has obs >= pd2_B, forcing pd2_B<=W -> B
// gets an exact 256-code scan which covers ANY rank in B.
__global__ __launch_bounds__(256)
void merge_flag(const float* __restrict__ pd1, const int* __restrict__ pi1,
                const float* __restrict__ pd2,
                int* __restrict__ idx, int* __restrict__ counters,
                unsigned long long* __restrict__ key,
                unsigned int* __restrict__ pairs, unsigned int* __restrict__ scans) {
    int n = blockIdx.x * 256 + threadIdx.x;
    float a = 3.4e38f, b2 = 3.4e38f; int ai = -1;
    for (int nb = 0; nb < NB_; ++nb) {
        float n1 = pd1[(size_t)nb * N_ + n];
        int   ni = pi1[(size_t)nb * N_ + n];
        float n2 = pd2[(size_t)nb * N_ + n];
        if (n1 < a) { b2 = fminf(a, n2); a = n1; ai = ni; }
        else        { b2 = fminf(b2, n1); }
    }
    if (b2 - a < MARGIN) {
        const float W = a + MARGIN;
        key[n] = ~0ULL;
        idx[n] = 0x80000000 | ai;          // flagged: resolve from key later
        for (int nb = 0; nb < NB_; ++nb) {
            if (pd2[(size_t)nb * N_ + n] <= W) {
                int q = atomicAdd(&counters[1], 1);
                scans[q] = ((unsigned)n << 5) | (unsigned)nb;
            } else if (pd1[(size_t)nb * N_ + n] <= W) {
                int q = atomicAdd(&counters[0], 1);
                pairs[q] = ((unsigned)n << 13) | (unsigned)pi1[(size_t)nb * N_ + n];
            }
        }
    } else {
        idx[n] = ai;
    }
}

// ---------------- fused exact fp32 recheck (pairs + block scans) ------------
// blocks [0,128): 4 threads per (token, candidate); blocks [128,384): one
// (token, 256-code block) exact scan per task, E rows coalesced.
__global__ __launch_bounds__(256)
void recheck(const float* __restrict__ x, const float* __restrict__ E,
             const float* __restrict__ c, const unsigned int* __restrict__ pairs,
             const unsigned int* __restrict__ scans, const int* __restrict__ counters,
             unsigned long long* __restrict__ key) {
    if (blockIdx.x < 128) {
        int items = counters[0] * 4;
        for (int it = blockIdx.x * 256 + threadIdx.x; it < items; it += 128 * 256) {
            int p = it >> 2, q = it & 3;   // quads stay intact: stride % 4 == 0
            unsigned v = pairs[p];
            int n = v >> 13, k = v & 8191;
            int b = n >> 10, s = n & 1023;
            const float* xb = x + (size_t)b * 262144 + s;
            const float* eb = E + k;
            float acc = 0.f;
            const int d0 = q * 64;
            #pragma unroll 8
            for (int d = d0; d < d0 + 64; ++d)
                acc = fmaf(xb[(size_t)d * HW_], eb[(size_t)d * K_], acc);
            float o1 = __shfl_xor(acc, 1); float s2 = acc + o1;
            float o2 = __shfl_xor(s2, 2);  float tot = s2 + o2;   // ((q0+q1)+(q2+q3))
            if (q == 0) atomicMin(key + n, pack_dk(fmaf(-2.f, tot, c[k]), k));
        }
    } else {
        int cnt = counters[1];
        for (int t = blockIdx.x - 128; t < cnt; t += 256) {
            unsigned v = scans[t];
            int n = v >> 5, nb = v & 31;
            int k = nb * 256 + threadIdx.x;
            int b = n >> 10, s = n & 1023;
            const float* xb = x + (size_t)b * 262144 + s;
            float acc = 0.f;
            #pragma unroll 4
            for (int d = 0; d < D_; ++d)          // ascending d: exact ref chain
                acc = fmaf(xb[(size_t)d * HW_], E[(size_t)d * K_ + k], acc);
            float dist = fmaf(-2.f, acc, c[k]);
            atomicMin(key + n, pack_dk(dist, k));  // (dist,k) lex-min: first-min ties
        }
    }
}

// ---------------- gather + write outputs (float4, fixup via sign bit) -------
// grid (256, 4): blockIdx.y selects a 64-d band -> 4 blocks/CU (was 1,
// latency-bound gather).
__global__ __launch_bounds__(256)
void write_kernel(const float* __restrict__ x, const float* __restrict__ E,
                  const int* __restrict__ idx, const unsigned long long* __restrict__ key,
                  float* __restrict__ out) {
    __shared__ int kst[64];
    const int n0 = blockIdx.x * 64;
    const int b = n0 >> 10, s0 = n0 & 1023;
    const int tid = threadIdx.x;
    if (tid < 64) {
        int v = idx[n0 + tid];
        int k = (v < 0) ? (int)(key[n0 + tid] & 8191ULL) : v;
        kst[tid] = k;
        if (blockIdx.y == 0) out[IND_OFF + n0 + tid] = (float)k;
    }
    __syncthreads();
    const int g = tid & 15;               // float4 group of 4 tokens
    const int d0 = tid >> 4;              // 16 d-streams
    const int dband = blockIdx.y * 64;    // this block's 64-d band
    const int ka = kst[g * 4], kb2 = kst[g * 4 + 1], kc = kst[g * 4 + 2], kd = kst[g * 4 + 3];
    const float* xb = x + (size_t)b * 262144 + s0 + g * 4;
    float* o0 = out + (size_t)b * 262144 + s0 + g * 4;
    float* o1 = o0 + OUT1_OFF;
    for (int d = dband + d0; d < dband + 64; d += 16) {
        const float* er = E + (size_t)d * K_;
        float4 xv = *(const float4*)(xb + (size_t)d * HW_);
        float4 q;
        q.x = er[ka]; q.y = er[kb2]; q.z = er[kc]; q.w = er[kd];
        float4 r;                          // x + (q - x): replicate jnp fp32 rounding
        r.x = xv.x + (q.x - xv.x); r.y = xv.y + (q.y - xv.y);
        r.z = xv.z + (q.z - xv.z); r.w = xv.w + (q.w - xv.w);
        *(float4*)(o0 + (size_t)d * HW_) = r;
        *(float4*)(o1 + (size_t)d * HW_) = q;
    }
}

extern "C" void kernel_launch(void* const* d_in, const int* in_sizes, int n_in,
                              void* d_out, int out_size, void* d_ws, size_t ws_size,
                              hipStream_t stream) {
    const float* x = (const float*)d_in[0];
    const float* E = (const float*)d_in[1];
    float* out = (float*)d_out;

    char* p = (char*)d_ws;
    ushort* xf = (ushort*)p;                 p += (size_t)N_ * D_ * 2;   // 8 MB
    ushort* ef = (ushort*)p;                 p += (size_t)K_ * D_ * 2;   // 4 MB
    float*  c  = (float*)p;                  p += (size_t)K_ * 4;
    float*  pd1 = (float*)p;                 p += (size_t)NB_ * N_ * 4;  // 2 MB
    int*    pi1 = (int*)p;                   p += (size_t)NB_ * N_ * 4;
    float*  pd2 = (float*)p;                 p += (size_t)NB_ * N_ * 4;
    int*    idx = (int*)p;                   p += (size_t)N_ * 4;
    unsigned long long* key = (unsigned long long*)p; p += (size_t)N_ * 8;
    unsigned int* pairs = (unsigned int*)p;  p += (size_t)524288 * 4;    // 2 MB cap
    unsigned int* scans = (unsigned int*)p;  p += (size_t)524288 * 4;    // 2 MB cap
    int*    counters = (int*)p;              p += 256;

    cnorm_kernel<<<K_ / 32, 256, 0, stream>>>(E, c, counters);
    prep_x<<<dim3(32, 8, 16), 256, 0, stream>>>(x, xf);
    prep_e<<<dim3(256, 8), 256, 0, stream>>>(E, ef);
    mfma_kernel<<<4096, 256, 0, stream>>>(xf, ef, c, pd1, pi1, pd2);
    merge_flag<<<N_ / 256, 256, 0, stream>>>(pd1, pi1, pd2, idx, counters, key, pairs, scans);
    recheck<<<384, 256, 0, stream>>>(x, E, c, pairs, scans, counters, key);
    write_kernel<<<dim3(256, 4), 256, 0, stream>>>(x, E, idx, key, out);
}

// Round 15
// 295.614 us; speedup vs baseline: 1.4813x; 1.0134x over previous
//
#include <hip/hip_runtime.h>
#include <hip/hip_bf16.h>
#include <hip/hip_fp16.h>

// VQ codebook lookup via fp16 MFMA + margin-based candidate recheck.
// x[16,256,32,32] f32, E[256,8192] f32, N=16384 tokens, K=8192 codes.
// S = fp16(x)·fp16(e) via mfma_f32_16x16x32_f16 (fp16 products exact in
// fp32): dist-err sigma ~7.8e-4, pairwise ~1.1e-3; MARGIN 0.02 ~ 18 sigma.
// Flagged tokens: block top-1s in window -> exact pair recheck; blocks with
// top-2 in window -> exact 256-code BLOCK scan. Exact path = ascending-d
// fmaf chain (validated R1-R8).
//
// R24 = R23 + prep-stage fusion (7 launches -> 5). R23 post-mortem: mfma
//   115.5us (spill fixed, LDS-port model validated); tail = ~184us across
//   SIX sequential dependent launches whose roofline sum is only ~60-80us
//   -> launch gaps dominate the tail. cnorm/prep_x/prep_e are mutually
//   independent: fused into ONE kernel partitioned by blockIdx
//   ([0,4096)=prep_x, [4096,6144)=prep_e, [6144,6400)=cnorm); per-thread
//   numerics byte-identical -> absmax-0 chain preserved.
//   mfma kernel untouched from R23 (at structural floor for validated
//   sync: 2 blocks/CU reg-bound, no pipe saturated, barrier-limited).
//   Kept (validated): fp16 single-pass (R14), 2-phase gload_lds dbuf
//   __syncthreads loop (R14/R19), 128x256 fat tile + launch_bounds(256,2)
//   (R23), XOR staging swizzle (R6/R7/R11), packed-u32 top-2 epilogue +
//   4-way write split (R17/R19), XCD both-operand L2 residency.
// Downstream kernels and pd1/pi1/pd2 layout unchanged from R19 (absmax 0).

#define D_   256
#define HW_  1024
#define N_   16384
#define K_   8192
#define NB_  32              // 32 code-blocks of 256
#define MARGIN 0.02f         // ~18 sigma of fp16 approx-error difference

#define OUT1_OFF 4194304     // B*D*H*W
#define IND_OFF  8388608

typedef __attribute__((ext_vector_type(8))) _Float16 f16x8;  // 8 f16 = 4 VGPR
typedef __attribute__((ext_vector_type(4))) float f32x4;

__device__ __forceinline__ unsigned long long pack_dk(float dist, int k) {
    unsigned db = __float_as_uint(dist);
    unsigned mono = (db & 0x80000000u) ? ~db : (db | 0x80000000u);
    return ((unsigned long long)mono << 32) | (unsigned)k;
}

// async global->LDS DMA: lane i of the wave lands at ldsbase + 16*i.
__device__ __forceinline__ void async_copy16(const void* g, void* l) {
    __builtin_amdgcn_global_load_lds(
        (const __attribute__((address_space(1))) void*)g,
        (__attribute__((address_space(3))) void*)l, 16, 0, 0);
}

// ---------------- fused prep: x->xf (fp16 T), E->ef (fp16 T), E->c norms ----
// blocks [0,4096): prep_x tile; [4096,6144): prep_e tile; [6144,6400): cnorm.
// Bodies byte-identical per-thread to the R23 kernels (absmax-0 chain).
__global__ __launch_bounds__(256)
void prep_all(const float* __restrict__ x, const float* __restrict__ E,
              ushort* __restrict__ xf, ushort* __restrict__ ef,
              float* __restrict__ c, int* __restrict__ counters) {
    __shared__ float t[32][33];
    const int tid = threadIdx.x;
    const int bid = blockIdx.x;
    if (bid < 4096) {
        // ---- prep_x: x fp32 -> fp16 plane, transposed to token-major ----
        const int s0 = (bid & 31) * 32, d0 = ((bid >> 5) & 7) * 32, b = bid >> 8;
        #pragma unroll
        for (int j = 0; j < 4; ++j) {
            int i = tid + 256 * j; int dd = i >> 5, ss = i & 31;
            t[dd][ss] = x[(size_t)b * 262144 + (size_t)(d0 + dd) * 1024 + s0 + ss];
        }
        __syncthreads();
        #pragma unroll
        for (int j = 0; j < 4; ++j) {
            int i = tid + 256 * j; int ss = i >> 5, dd = i & 31;
            _Float16 h = (_Float16)t[dd][ss];          // RN f32->f16
            size_t o = (size_t)(b * 1024 + s0 + ss) * D_ + d0 + dd;
            xf[o] = *(ushort*)&h;
        }
    } else if (bid < 6144) {
        // ---- prep_e: E[d][k] -> ef[k][d] fp16 ----
        const int e2 = bid - 4096;
        const int k0 = (e2 & 255) * 32, d0 = (e2 >> 8) * 32;
        #pragma unroll
        for (int j = 0; j < 4; ++j) {
            int i = tid + 256 * j; int dd = i >> 5, kk = i & 31;
            t[dd][kk] = E[(size_t)(d0 + dd) * K_ + k0 + kk];
        }
        __syncthreads();
        #pragma unroll
        for (int j = 0; j < 4; ++j) {
            int i = tid + 256 * j; int kk = i >> 5, dd = i & 31;
            _Float16 h = (_Float16)t[dd][kk];
            ef[(size_t)(k0 + kk) * D_ + d0 + dd] = *(ushort*)&h;
        }
    } else {
        // ---- cnorm: codebook column norms + counter zeroing ----
        const int kb = bid - 6144;
        if (kb == 0 && tid < 2) counters[tid] = 0;
        float* part = &t[0][0];                        // [8][32] flat overlay
        const int cl = tid & 31, q = tid >> 5;
        const int k = kb * 32 + cl;
        float s = 0.f;
        #pragma unroll 8
        for (int d = q * 32; d < q * 32 + 32; ++d) {
            float v = E[(size_t)d * K_ + k];
            s = fmaf(v, v, s);
        }
        part[q * 32 + cl] = s;
        __syncthreads();
        if (tid < 32) {   // fixed combine order: deterministic
            float t0 = (part[0 * 32 + tid] + part[1 * 32 + tid]) + (part[2 * 32 + tid] + part[3 * 32 + tid]);
            float t1 = (part[4 * 32 + tid] + part[5 * 32 + tid]) + (part[6 * 32 + tid] + part[7 * 32 + tid]);
            c[kb * 32 + tid] = t0 + t1;
        }
    }
}

// ---------------- MFMA distance + per-token top-2 per 256-code block --------
// grid 4096 flat, XCD-partitioned. block 256 = 4 waves (2x2), block tile
// 128 tokens x 256 codes, wave tile 64x128 (acc[4][8]). 2-phase dbuf,
// prefetch t+1 before compute of t, one __syncthreads per step. LDS rows =
// 64B of 4x16B chunks, chunk position = chunk ^ ((row>>1)&3) — conflict-free
// (R6/R7/R11-verified). Packed-u32 top-2 epilogue (R17/R19-validated).
__global__ __launch_bounds__(256, 2)
void mfma_kernel(const ushort* __restrict__ xf,
                 const ushort* __restrict__ ef,
                 const float* __restrict__ c,
                 float* __restrict__ pd1, int* __restrict__ pi1, float* __restrict__ pd2) {
    __shared__ __align__(16) ushort Af[2][4096];   // [2][128*32] 16 KB
    __shared__ __align__(16) ushort Bf[2][8192];   // [2][256*32] 32 KB
    __shared__ unsigned red1[384], red2[384];      // [128][3] stride-3: conflict-free

    const int tid = threadIdx.x;
    // XCD partition: xcd owns mb in [xcd*16, xcd*16+16); nb slow within xcd.
    const int bid = blockIdx.x;
    const int xcd = bid & 7, rr = bid >> 3;        // rr in [0,512)
    const int nb = rr >> 4, mb = xcd * 16 + (rr & 15);
    const int n0 = mb * 128, k0 = nb * 256;
    const int lane = tid & 63, w = tid >> 6;
    const int wy = w >> 1, wx = w & 1;             // 2x2 wave layout
    const int l15 = lane & 15, lq = lane >> 4;

    // A staging: 2 gload_lds per wave per step (4 waves cover 128 rows)
    size_t aoff[2]; int adst[2];
    #pragma unroll
    for (int g = 0; g < 2; ++g) {
        int slot = (w * 2 + g) * 64 + lane;
        int t = slot >> 2, cp = slot & 3;
        int cs = cp ^ ((t >> 1) & 3);
        aoff[g] = (size_t)(n0 + t) * D_ + cs * 8;
        adst[g] = (w * 2 + g) * 512;
    }
    // B staging: 4 gload_lds per wave per step
    size_t boff[4]; int bdst[4];
    #pragma unroll
    for (int g = 0; g < 4; ++g) {
        int slot = (w * 4 + g) * 64 + lane;
        int t = slot >> 2, cp = slot & 3;
        int cs = cp ^ ((t >> 1) & 3);
        boff[g] = (size_t)(k0 + t) * D_ + cs * 8;
        bdst[g] = (w * 4 + g) * 512;
    }
    // fragment read offsets (XOR matches staging swizzle)
    int aro[4], bro[8];
    #pragma unroll
    for (int mt = 0; mt < 4; ++mt) {
        int R = wy * 64 + mt * 16 + l15;
        aro[mt] = R * 32 + ((lq ^ ((R >> 1) & 3)) * 8);
    }
    #pragma unroll
    for (int nt = 0; nt < 8; ++nt) {
        int R = wx * 128 + nt * 16 + l15;
        bro[nt] = R * 32 + ((lq ^ ((R >> 1) & 3)) * 8);
    }

    f32x4 acc[4][8];
    #pragma unroll
    for (int mt = 0; mt < 4; ++mt)
        #pragma unroll
        for (int nt = 0; nt < 8; ++nt) acc[mt][nt] = (f32x4){0.f, 0.f, 0.f, 0.f};

    // prologue: stage step 0 into buffer 0
    #pragma unroll
    for (int g = 0; g < 2; ++g)
        async_copy16(xf + aoff[g], &Af[0][adst[g]]);
    #pragma unroll
    for (int g = 0; g < 4; ++g)
        async_copy16(ef + boff[g], &Bf[0][bdst[g]]);
    __syncthreads();

    #pragma unroll
    for (int db = 0; db < 8; ++db) {
        const int cur = db & 1;
        const int d0 = db * 32;
        if (db < 7) {   // prefetch step t+1 into the other buffer
            const int dn = d0 + 32;
            #pragma unroll
            for (int g = 0; g < 2; ++g)
                async_copy16(xf + aoff[g] + dn, &Af[cur ^ 1][adst[g]]);
            #pragma unroll
            for (int g = 0; g < 4; ++g)
                async_copy16(ef + boff[g] + dn, &Bf[cur ^ 1][bdst[g]]);
        }
        f16x8 a[4];
        #pragma unroll
        for (int mt = 0; mt < 4; ++mt)
            a[mt] = *(const f16x8*)&Af[cur][aro[mt]];
        #pragma unroll
        for (int nt = 0; nt < 8; ++nt) {
            f16x8 b = *(const f16x8*)&Bf[cur][bro[nt]];
            #pragma unroll
            for (int mt = 0; mt < 4; ++mt)
                acc[mt][nt] = __builtin_amdgcn_mfma_f32_16x16x32_f16(a[mt], b, acc[mt][nt], 0, 0, 0);
        }
        __syncthreads();   // drains prefetch; protects buffer reuse
    }

    float cv[8];
    #pragma unroll
    for (int nt = 0; nt < 8; ++nt) cv[nt] = c[k0 + wx * 128 + nt * 16 + l15];

    // packed top-2: key = ((uint)((dist+128)*2^15) << 8) | code8.
    // dist bounded |dist| <= 1+2*||x||·||e|| < 40 << 128; quant step ~8e-6
    // absorbed by MARGIN (18 sigma). min = dist asc then code asc
    // (= first-min ties). R17/R19-validated (absmax 0).
    unsigned m1[16], m2[16];
    #pragma unroll
    for (int mt = 0; mt < 4; ++mt)
        #pragma unroll
        for (int r = 0; r < 4; ++r) {
            int p = mt * 4 + r;
            unsigned b1 = 0xFFFFFFFFu, b2v = 0xFFFFFFFFu;
            #pragma unroll
            for (int nt = 0; nt < 8; ++nt) {
                float dist = fmaf(-2.f, acc[mt][nt][r], cv[nt]);
                unsigned u = (unsigned)fmaf(dist, 32768.f, 4194304.f); // (d+128)*2^15
                unsigned key = (u << 8) | (unsigned)(wx * 128 + nt * 16 + l15);
                unsigned t = key > b1 ? key : b1;    // max
                b1 = key < b1 ? key : b1;            // min
                b2v = t < b2v ? t : b2v;             // min
            }
            m1[p] = b1; m2[p] = b2v;
        }
    #pragma unroll
    for (int s = 1; s < 16; s <<= 1) {
        #pragma unroll
        for (int p = 0; p < 16; ++p) {
            unsigned n1 = (unsigned)__shfl_xor((int)m1[p], s);
            unsigned n2 = (unsigned)__shfl_xor((int)m2[p], s);
            unsigned t = m1[p] > n1 ? m1[p] : n1;
            m1[p] = m1[p] < n1 ? m1[p] : n1;
            unsigned mn = n2 < t ? n2 : t;
            m2[p] = m2[p] < mn ? m2[p] : mn;         // min3(m2, n2, t)
        }
    }
    if (l15 == 0) {
        #pragma unroll
        for (int mt = 0; mt < 4; ++mt)
            #pragma unroll
            for (int r = 0; r < 4; ++r) {
                int p = mt * 4 + r;
                int t = wy * 64 + mt * 16 + lq * 4 + r;   // token 0..127
                red1[t * 3 + wx] = m1[p]; red2[t * 3 + wx] = m2[p];
            }
    }
    __syncthreads();
    if (tid < 128) {   // order-independent min/max merge: deterministic
        unsigned a1 = red1[tid * 3], a2v = red2[tid * 3];
        unsigned n1 = red1[tid * 3 + 1], n2 = red2[tid * 3 + 1];
        unsigned t = a1 > n1 ? a1 : n1;
        a1 = a1 < n1 ? a1 : n1;
        unsigned mn = n2 < t ? n2 : t;
        a2v = a2v < mn ? a2v : mn;
        size_t o = (size_t)nb * N_ + n0 + tid;
        pd1[o] = (float)(a1 >> 8) * (1.f / 32768.f) - 128.f;
        pi1[o] = k0 + (int)(a1 & 255u);
        pd2[o] = (float)(a2v >> 8) * (1.f / 32768.f) - 128.f;
    }
}

// ---------------- merge 32 blocks; enumerate pair/scan candidates -----------
// counters[0]=pairs, [1]=block-scan tasks. Coverage: true winner j in block B
// is B's top-1 (pd1<=W -> pair) or has obs >= pd2_B, forcing pd2_B<=W -> B
// gets an exact 256-code scan which covers ANY rank in B.
__global__ __launch_bounds__(256)
void merge_flag(const float* __restrict__ pd1, const int* __restrict__ pi1,
                const float* __restrict__ pd2,
                int* __restrict__ idx, int* __restrict__ counters,
                unsigned long long* __restrict__ key,
                unsigned int* __restrict__ pairs, unsigned int* __restrict__ scans) {
    int n = blockIdx.x * 256 + threadIdx.x;
    float a = 3.4e38f, b2 = 3.4e38f; int ai = -1;
    for (int nb = 0; nb < NB_; ++nb) {
        float n1 = pd1[(size_t)nb * N_ + n];
        int   ni = pi1[(size_t)nb * N_ + n];
        float n2 = pd2[(size_t)nb * N_ + n];
        if (n1 < a) { b2 = fminf(a, n2); a = n1; ai = ni; }
        else        { b2 = fminf(b2, n1); }
    }
    if (b2 - a < MARGIN) {
        const float W = a + MARGIN;
        key[n] = ~0ULL;
        idx[n] = 0x80000000 | ai;          // flagged: resolve from key later
        for (int nb = 0; nb < NB_; ++nb) {
            if (pd2[(size_t)nb * N_ + n] <= W) {
                int q = atomicAdd(&counters[1], 1);
                scans[q] = ((unsigned)n << 5) | (unsigned)nb;
            } else if (pd1[(size_t)nb * N_ + n] <= W) {
                int q = atomicAdd(&counters[0], 1);
                pairs[q] = ((unsigned)n << 13) | (unsigned)pi1[(size_t)nb * N_ + n];
            }
        }
    } else {
        idx[n] = ai;
    }
}

// ---------------- fused exact fp32 recheck (pairs + block scans) ------------
// blocks [0,128): 4 threads per (token, candidate); blocks [128,384): one
// (token, 256-code block) exact scan per task, E rows coalesced.
__global__ __launch_bounds__(256)
void recheck(const float* __restrict__ x, const float* __restrict__ E,
             const float* __restrict__ c, const unsigned int* __restrict__ pairs,
             const unsigned int* __restrict__ scans, const int* __restrict__ counters,
             unsigned long long* __restrict__ key) {
    if (blockIdx.x < 128) {
        int items = counters[0] * 4;
        for (int it = blockIdx.x * 256 + threadIdx.x; it < items; it += 128 * 256) {
            int p = it >> 2, q = it & 3;   // quads stay intact: stride % 4 == 0
            unsigned v = pairs[p];
            int n = v >> 13, k = v & 8191;
            int b = n >> 10, s = n & 1023;
            const float* xb = x + (size_t)b * 262144 + s;
            const float* eb = E + k;
            float acc = 0.f;
            const int d0 = q * 64;
            #pragma unroll 8
            for (int d = d0; d < d0 + 64; ++d)
                acc = fmaf(xb[(size_t)d * HW_], eb[(size_t)d * K_], acc);
            float o1 = __shfl_xor(acc, 1); float s2 = acc + o1;
            float o2 = __shfl_xor(s2, 2);  float tot = s2 + o2;   // ((q0+q1)+(q2+q3))
            if (q == 0) atomicMin(key + n, pack_dk(fmaf(-2.f, tot, c[k]), k));
        }
    } else {
        int cnt = counters[1];
        for (int t = blockIdx.x - 128; t < cnt; t += 256) {
            unsigned v = scans[t];
            int n = v >> 5, nb = v & 31;
            int k = nb * 256 + threadIdx.x;
            int b = n >> 10, s = n & 1023;
            const float* xb = x + (size_t)b * 262144 + s;
            float acc = 0.f;
            #pragma unroll 4
            for (int d = 0; d < D_; ++d)          // ascending d: exact ref chain
                acc = fmaf(xb[(size_t)d * HW_], E[(size_t)d * K_ + k], acc);
            float dist = fmaf(-2.f, acc, c[k]);
            atomicMin(key + n, pack_dk(dist, k));  // (dist,k) lex-min: first-min ties
        }
    }
}

// ---------------- gather + write outputs (float4, fixup via sign bit) -------
// grid (256, 4): blockIdx.y selects a 64-d band -> 4 blocks/CU (was 1,
// latency-bound gather).
__global__ __launch_bounds__(256)
void write_kernel(const float* __restrict__ x, const float* __restrict__ E,
                  const int* __restrict__ idx, const unsigned long long* __restrict__ key,
                  float* __restrict__ out) {
    __shared__ int kst[64];
    const int n0 = blockIdx.x * 64;
    const int b = n0 >> 10, s0 = n0 & 1023;
    const int tid = threadIdx.x;
    if (tid < 64) {
        int v = idx[n0 + tid];
        int k = (v < 0) ? (int)(key[n0 + tid] & 8191ULL) : v;
        kst[tid] = k;
        if (blockIdx.y == 0) out[IND_OFF + n0 + tid] = (float)k;
    }
    __syncthreads();
    const int g = tid & 15;               // float4 group of 4 tokens
    const int d0 = tid >> 4;              // 16 d-streams
    const int dband = blockIdx.y * 64;    // this block's 64-d band
    const int ka = kst[g * 4], kb2 = kst[g * 4 + 1], kc = kst[g * 4 + 2], kd = kst[g * 4 + 3];
    const float* xb = x + (size_t)b * 262144 + s0 + g * 4;
    float* o0 = out + (size_t)b * 262144 + s0 + g * 4;
    float* o1 = o0 + OUT1_OFF;
    for (int d = dband + d0; d < dband + 64; d += 16) {
        const float* er = E + (size_t)d * K_;
        float4 xv = *(const float4*)(xb + (size_t)d * HW_);
        float4 q;
        q.x = er[ka]; q.y = er[kb2]; q.z = er[kc]; q.w = er[kd];
        float4 r;                          // x + (q - x): replicate jnp fp32 rounding
        r.x = xv.x + (q.x - xv.x); r.y = xv.y + (q.y - xv.y);
        r.z = xv.z + (q.z - xv.z); r.w = xv.w + (q.w - xv.w);
        *(float4*)(o0 + (size_t)d * HW_) = r;
        *(float4*)(o1 + (size_t)d * HW_) = q;
    }
}

extern "C" void kernel_launch(void* const* d_in, const int* in_sizes, int n_in,
                              void* d_out, int out_size, void* d_ws, size_t ws_size,
                              hipStream_t stream) {
    const float* x = (const float*)d_in[0];
    const float* E = (const float*)d_in[1];
    float* out = (float*)d_out;

    char* p = (char*)d_ws;
    ushort* xf = (ushort*)p;                 p += (size_t)N_ * D_ * 2;   // 8 MB
    ushort* ef = (ushort*)p;                 p += (size_t)K_ * D_ * 2;   // 4 MB
    float*  c  = (float*)p;                  p += (size_t)K_ * 4;
    float*  pd1 = (float*)p;                 p += (size_t)NB_ * N_ * 4;  // 2 MB
    int*    pi1 = (int*)p;                   p += (size_t)NB_ * N_ * 4;
    float*  pd2 = (float*)p;                 p += (size_t)NB_ * N_ * 4;
    int*    idx = (int*)p;                   p += (size_t)N_ * 4;
    unsigned long long* key = (unsigned long long*)p; p += (size_t)N_ * 8;
    unsigned int* pairs = (unsigned int*)p;  p += (size_t)524288 * 4;    // 2 MB cap
    unsigned int* scans = (unsigned int*)p;  p += (size_t)524288 * 4;    // 2 MB cap
    int*    counters = (int*)p;              p += 256;

    prep_all<<<6400, 256, 0, stream>>>(x, E, xf, ef, c, counters);
    mfma_kernel<<<4096, 256, 0, stream>>>(xf, ef, c, pd1, pi1, pd2);
    merge_flag<<<N_ / 256, 256, 0, stream>>>(pd1, pi1, pd2, idx, counters, key, pairs, scans);
    recheck<<<384, 256, 0, stream>>>(x, E, c, pairs, scans, counters, key);
    write_kernel<<<dim3(256, 4), 256, 0, stream>>>(x, E, idx, key, out);
}